// Round 5
// baseline (277.815 us; speedup 1.0000x reference)
//
#include <hip/hip_runtime.h>

#define NN 50000
#define NE 800000
#define NF 128
#define DIM 32
#define NG 500
#define BK 64                         // nodes per bucket
#define NB ((NN + BK - 1) / BK)       // 782 buckets
#define HB 64                         // histogram/partition blocks
#define CHUNK_E ((NE + HB - 1) / HB)  // 12500 edges per block
#define SC_CHUNK 4                    // 256*4 >= NB

// ---------- k1: y = x@w_rel ; root = x@w_root + b_rel ----------
__global__ __launch_bounds__(256) void proj_kernel(
    const float* __restrict__ x, const float* __restrict__ w_rel,
    const float* __restrict__ w_root, const float* __restrict__ b_rel,
    float* __restrict__ y, float* __restrict__ root)
{
    __shared__ float s_w[2 * NF * DIM];   // 32 KB
    __shared__ float s_x[32 * NF];        // 16 KB
    int tid = threadIdx.x;
#pragma unroll
    for (int j = 0; j < 16; ++j) {
        s_w[tid + j * 256]        = w_rel[tid + j * 256];
        s_w[4096 + tid + j * 256] = w_root[tid + j * 256];
    }
    int rb = blockIdx.x * 32;
#pragma unroll
    for (int j = 0; j < 16; ++j) {
        int idx = rb * NF + tid + j * 256;
        s_x[tid + j * 256] = (idx < NN * NF) ? x[idx] : 0.0f;
    }
    __syncthreads();

    int col = tid & 31;
    int sel = (tid >> 5) & 1;      // 0 -> y (w_rel), 1 -> root (w_root + b_rel)
    int r0  = (tid >> 6) * 8;      // 8 rows per thread (wave-uniform)
    const float* W = s_w + sel * 4096;
    float bias = sel ? b_rel[col] : 0.0f;
    float acc[8];
#pragma unroll
    for (int j = 0; j < 8; ++j) acc[j] = bias;
    const float* xr = s_x + r0 * NF;
#pragma unroll 8
    for (int k = 0; k < NF; k += 4) {
        float w0 = W[(k + 0) * DIM + col];
        float w1 = W[(k + 1) * DIM + col];
        float w2 = W[(k + 2) * DIM + col];
        float w3 = W[(k + 3) * DIM + col];
#pragma unroll
        for (int j = 0; j < 8; ++j) {
            float4 xv = *reinterpret_cast<const float4*>(&xr[j * NF + k]);
            acc[j] = fmaf(xv.x, w0, acc[j]);
            acc[j] = fmaf(xv.y, w1, acc[j]);
            acc[j] = fmaf(xv.z, w2, acc[j]);
            acc[j] = fmaf(xv.w, w3, acc[j]);
        }
    }
    float* dst = sel ? root : y;
#pragma unroll
    for (int j = 0; j < 8; ++j) {
        int row = rb + r0 + j;
        if (row < NN) dst[row * DIM + col] = acc[j];
    }
}

// ---------- k2: per-block bucket histogram (LDS) -> H[blk][bucket] ----------
__global__ __launch_bounds__(256) void histk(
    const int* __restrict__ ei, int* __restrict__ H)
{
    __shared__ int sh[NB];
    int t = threadIdx.x;
    for (int i = t; i < NB; i += 256) sh[i] = 0;
    __syncthreads();
    int base = blockIdx.x * CHUNK_E;
    int end  = min(base + CHUNK_E, NE);
    for (int e = base + t; e < end; e += 256)
        atomicAdd(&sh[ei[NE + e] >> 6], 1);
    __syncthreads();
    for (int i = t; i < NB; i += 256) H[blockIdx.x * NB + i] = sh[i];
}

// ---------- k3a: in-place column prefix over blocks; colsum[b] = total ----------
__global__ __launch_bounds__(256) void colscan(
    int* __restrict__ H, int* __restrict__ colsum)
{
    int b = blockIdx.x * 256 + threadIdx.x;
    if (b >= NB) return;
    int run = 0;
#pragma unroll 4
    for (int blk = 0; blk < HB; ++blk) {
        int v = H[blk * NB + b];   // coalesced across threads (b contiguous)
        H[blk * NB + b] = run;     // exclusive prefix within column
        run += v;
    }
    colsum[b] = run;
}

// ---------- k3b: exclusive scan of colsum -> boff (bucket offsets) ----------
__global__ __launch_bounds__(256) void bscan2(
    const int* __restrict__ colsum, int* __restrict__ boff)
{
    __shared__ int s[256];
    int t = threadIdx.x;
    int v[SC_CHUNK];
    int sum = 0;
#pragma unroll
    for (int j = 0; j < SC_CHUNK; ++j) {
        int idx = t * SC_CHUNK + j;
        v[j] = (idx < NB) ? colsum[idx] : 0;
        sum += v[j];
    }
    s[t] = sum;
    __syncthreads();
    for (int o = 1; o < 256; o <<= 1) {
        int u = (t >= o) ? s[t - o] : 0;
        __syncthreads();
        s[t] += u;
        __syncthreads();
    }
    int base = s[t] - sum;
#pragma unroll
    for (int j = 0; j < SC_CHUNK; ++j) {
        int idx = t * SC_CHUNK + j;
        if (idx < NB) { boff[idx] = base; base += v[j]; }
    }
    if (t == 0) boff[NB] = NE;
}

// ---------- k4: deterministic partition via LDS cursors (no global atomics) ----------
__global__ __launch_bounds__(256) void partition_kernel(
    const int* __restrict__ ei, const float* __restrict__ ew,
    const int* __restrict__ H, const int* __restrict__ boff,
    uint2* __restrict__ part)
{
    __shared__ int cur[NB];
    int t = threadIdx.x;
    for (int i = t; i < NB; i += 256)
        cur[i] = boff[i] + H[blockIdx.x * NB + i];
    __syncthreads();
    int base = blockIdx.x * CHUNK_E;
    int end  = min(base + CHUNK_E, NE);
    for (int e = base + t; e < end; e += 256) {
        int s = ei[e], d = ei[NE + e];
        float w = ew[e];
        int b = d >> 6;
        int pos = atomicAdd(&cur[b], 1);   // LDS atomic, block-local
        part[pos] = make_uint2((unsigned)s | ((unsigned)(d & 63) << 16),
                               __float_as_uint(w));
    }
}

// ---------- k5: bucket aggregate (LDS acc) + root + relu + pool ----------
__global__ __launch_bounds__(256) void bucketagg_kernel(
    const float* __restrict__ y, const float* __restrict__ root,
    const int* __restrict__ boff, const uint2* __restrict__ part,
    const int* __restrict__ batch, float* __restrict__ pooled)
{
    __shared__ float acc[BK * DIM];   // 8 KB
    int t = threadIdx.x;
    int b = blockIdx.x;
#pragma unroll
    for (int i = 0; i < BK * DIM / 256; ++i) acc[t + i * 256] = 0.0f;
    __syncthreads();

    int gi = t >> 5, c = t & 31;      // 8 edge-groups x 32 cols
    int e0 = boff[b], e1 = boff[b + 1];
    int e = e0 + gi;
    for (; e + 24 < e1; e += 32) {
        uint2 p0 = part[e], p1 = part[e + 8], p2 = part[e + 16], p3 = part[e + 24];
        float v0 = y[(p0.x & 0xFFFFu) * DIM + c] * __uint_as_float(p0.y);
        float v1 = y[(p1.x & 0xFFFFu) * DIM + c] * __uint_as_float(p1.y);
        float v2 = y[(p2.x & 0xFFFFu) * DIM + c] * __uint_as_float(p2.y);
        float v3 = y[(p3.x & 0xFFFFu) * DIM + c] * __uint_as_float(p3.y);
        atomicAdd(&acc[(p0.x >> 16) * DIM + c], v0);
        atomicAdd(&acc[(p1.x >> 16) * DIM + c], v1);
        atomicAdd(&acc[(p2.x >> 16) * DIM + c], v2);
        atomicAdd(&acc[(p3.x >> 16) * DIM + c], v3);
    }
    for (; e < e1; e += 8) {
        uint2 pk = part[e];
        float v = y[(pk.x & 0xFFFFu) * DIM + c] * __uint_as_float(pk.y);
        atomicAdd(&acc[(pk.x >> 16) * DIM + c], v);
    }
    __syncthreads();

    // fused root + relu + graph pooling; group gi owns local nodes [gi*8, gi*8+8)
    int curg = -1;
    float run = 0.0f;
#pragma unroll
    for (int j = 0; j < 8; ++j) {
        int nl = gi * 8 + j;
        int n  = b * BK + nl;
        if (n < NN) {
            float v = acc[nl * DIM + c] + root[n * DIM + c];
            v = fmaxf(v, 0.0f);
            int g = batch[n];
            if (g != curg) {
                if (curg >= 0) atomicAdd(&pooled[curg * DIM + c], run);
                curg = g;
                run  = v;
            } else {
                run += v;
            }
        }
    }
    if (curg >= 0) atomicAdd(&pooled[curg * DIM + c], run);
}

// ---------- k6: MLP head + log_softmax ----------
__global__ __launch_bounds__(512) void head_kernel(
    const float* __restrict__ pooled, const float* __restrict__ w_fc1,
    const float* __restrict__ b_fc1, const float* __restrict__ w_fc2,
    const float* __restrict__ b_fc2, float* __restrict__ out)
{
    __shared__ float s_fc1[DIM * DIM];
    __shared__ float s_b1[DIM];
    __shared__ float s_fc2[DIM * 2];
    __shared__ float s_b2[2];
    int tid = threadIdx.x;
    s_fc1[tid]       = w_fc1[tid];
    s_fc1[tid + 512] = w_fc1[tid + 512];
    if (tid < DIM * 2) s_fc2[tid] = w_fc2[tid];
    if (tid < DIM)     s_b1[tid]  = b_fc1[tid];
    if (tid < 2)       s_b2[tid]  = b_fc2[tid];
    __syncthreads();

    int g = tid;
    if (g >= NG) return;
    const float* p = pooled + g * DIM;
    float h2[DIM];
#pragma unroll
    for (int c = 0; c < DIM; ++c) {
        float a = s_b1[c];
#pragma unroll
        for (int k = 0; k < DIM; ++k)
            a = fmaf(p[k], s_fc1[k * DIM + c], a);
        h2[c] = a > 0.0f ? a : 0.0f;
    }
    float l0 = s_b2[0], l1 = s_b2[1];
#pragma unroll
    for (int c = 0; c < DIM; ++c) {
        l0 = fmaf(h2[c], s_fc2[c * 2 + 0], l0);
        l1 = fmaf(h2[c], s_fc2[c * 2 + 1], l1);
    }
    float m   = fmaxf(l0, l1);
    float lse = m + logf(expf(l0 - m) + expf(l1 - m));
    out[g * 2 + 0] = l0 - lse;
    out[g * 2 + 1] = l1 - lse;
}

extern "C" void kernel_launch(void* const* d_in, const int* in_sizes, int n_in,
                              void* d_out, int out_size, void* d_ws, size_t ws_size,
                              hipStream_t stream) {
    const float* x      = (const float*)d_in[0];
    const float* ew     = (const float*)d_in[1];
    const float* w_rel  = (const float*)d_in[2];
    const float* b_rel  = (const float*)d_in[3];
    const float* w_root = (const float*)d_in[4];
    const float* w_fc1  = (const float*)d_in[5];
    const float* b_fc1  = (const float*)d_in[6];
    const float* w_fc2  = (const float*)d_in[7];
    const float* b_fc2  = (const float*)d_in[8];
    const int*   ei     = (const int*)d_in[9];
    const int*   batch  = (const int*)d_in[10];
    float* out = (float*)d_out;

    char* ws = (char*)d_ws;
    float* y      = (float*)ws;                               // 6.4 MB
    float* root   = y + (size_t)NN * DIM;                     // 6.4 MB
    uint2* part   = (uint2*)(root + (size_t)NN * DIM);        // 6.4 MB
    int*   H      = (int*)(part + NE);                        // HB*NB = 200 KB
    int*   colsum = H + HB * NB;                              // NB
    int*   boff   = colsum + NB;                              // NB+1
    float* pooled = (float*)(boff + NB + 2);                  // 64 KB

    hipMemsetAsync(pooled, 0, NG * DIM * sizeof(float), stream);

    proj_kernel<<<(NN + 31) / 32, 256, 0, stream>>>(x, w_rel, w_root, b_rel, y, root);
    histk<<<HB, 256, 0, stream>>>(ei, H);
    colscan<<<(NB + 255) / 256, 256, 0, stream>>>(H, colsum);
    bscan2<<<1, 256, 0, stream>>>(colsum, boff);
    partition_kernel<<<HB, 256, 0, stream>>>(ei, ew, H, boff, part);
    bucketagg_kernel<<<NB, 256, 0, stream>>>(y, root, boff, part, batch, pooled);
    head_kernel<<<1, 512, 0, stream>>>(pooled, w_fc1, b_fc1, w_fc2, b_fc2, out);
}

// Round 6
// 135.288 us; speedup vs baseline: 2.0535x; 2.0535x over previous
//
#include <hip/hip_runtime.h>

#define NN 50000
#define NE 800000
#define NF 128
#define DIM 32
#define NG 500
#define BK 64                         // nodes per bucket
#define NB ((NN + BK - 1) / BK)       // 782 buckets
#define HB 128                        // histogram/partition blocks
#define CHUNK_E ((NE + HB - 1) / HB)  // 6250 edges per block
#define SC_CHUNK 4                    // 256*4 >= NB

// ---------- k1: y = x@w_rel ; root = x@w_root + b_rel ----------
__global__ __launch_bounds__(256) void proj_kernel(
    const float* __restrict__ x, const float* __restrict__ w_rel,
    const float* __restrict__ w_root, const float* __restrict__ b_rel,
    float* __restrict__ y, float* __restrict__ root)
{
    __shared__ float s_w[2 * NF * DIM];   // 32 KB
    __shared__ float s_x[32 * NF];        // 16 KB
    int tid = threadIdx.x;
#pragma unroll
    for (int j = 0; j < 16; ++j) {
        s_w[tid + j * 256]        = w_rel[tid + j * 256];
        s_w[4096 + tid + j * 256] = w_root[tid + j * 256];
    }
    int rb = blockIdx.x * 32;
#pragma unroll
    for (int j = 0; j < 16; ++j) {
        int idx = rb * NF + tid + j * 256;
        s_x[tid + j * 256] = (idx < NN * NF) ? x[idx] : 0.0f;
    }
    __syncthreads();

    int col = tid & 31;
    int sel = (tid >> 5) & 1;      // 0 -> y (w_rel), 1 -> root (w_root + b_rel)
    int r0  = (tid >> 6) * 8;      // 8 rows per thread (wave-uniform)
    const float* W = s_w + sel * 4096;
    float bias = sel ? b_rel[col] : 0.0f;
    float acc[8];
#pragma unroll
    for (int j = 0; j < 8; ++j) acc[j] = bias;
    const float* xr = s_x + r0 * NF;
#pragma unroll 8
    for (int k = 0; k < NF; k += 4) {
        float w0 = W[(k + 0) * DIM + col];
        float w1 = W[(k + 1) * DIM + col];
        float w2 = W[(k + 2) * DIM + col];
        float w3 = W[(k + 3) * DIM + col];
#pragma unroll
        for (int j = 0; j < 8; ++j) {
            float4 xv = *reinterpret_cast<const float4*>(&xr[j * NF + k]);
            acc[j] = fmaf(xv.x, w0, acc[j]);
            acc[j] = fmaf(xv.y, w1, acc[j]);
            acc[j] = fmaf(xv.z, w2, acc[j]);
            acc[j] = fmaf(xv.w, w3, acc[j]);
        }
    }
    float* dst = sel ? root : y;
#pragma unroll
    for (int j = 0; j < 8; ++j) {
        int row = rb + r0 + j;
        if (row < NN) dst[row * DIM + col] = acc[j];
    }
}

// ---------- k2: per-block bucket histogram (LDS) -> H[blk][bucket] ----------
__global__ __launch_bounds__(256) void histk(
    const int* __restrict__ ei, int* __restrict__ H)
{
    __shared__ int sh[NB];
    int t = threadIdx.x;
    for (int i = t; i < NB; i += 256) sh[i] = 0;
    __syncthreads();
    int base = blockIdx.x * CHUNK_E;
    int end  = min(base + CHUNK_E, NE);
    for (int e = base + t; e < end; e += 256)
        atomicAdd(&sh[ei[NE + e] >> 6], 1);
    __syncthreads();
    for (int i = t; i < NB; i += 256) H[blockIdx.x * NB + i] = sh[i];
}

// ---------- k3a: column prefix over the HB block rows ----------
__global__ __launch_bounds__(256) void colscan(
    int* __restrict__ H, int* __restrict__ colsum)
{
    int b = blockIdx.x * 256 + threadIdx.x;
    if (b >= NB) return;
    int run = 0;
#pragma unroll 8
    for (int blk = 0; blk < HB; ++blk) {
        int v = H[blk * NB + b];   // coalesced across threads
        H[blk * NB + b] = run;
        run += v;
    }
    colsum[b] = run;
}

// ---------- k3b: exclusive scan of colsum -> boff ----------
__global__ __launch_bounds__(256) void bscan2(
    const int* __restrict__ colsum, int* __restrict__ boff)
{
    __shared__ int s[256];
    int t = threadIdx.x;
    int v[SC_CHUNK];
    int sum = 0;
#pragma unroll
    for (int j = 0; j < SC_CHUNK; ++j) {
        int idx = t * SC_CHUNK + j;
        v[j] = (idx < NB) ? colsum[idx] : 0;
        sum += v[j];
    }
    s[t] = sum;
    __syncthreads();
    for (int o = 1; o < 256; o <<= 1) {
        int u = (t >= o) ? s[t - o] : 0;
        __syncthreads();
        s[t] += u;
        __syncthreads();
    }
    int base = s[t] - sum;
#pragma unroll
    for (int j = 0; j < SC_CHUNK; ++j) {
        int idx = t * SC_CHUNK + j;
        if (idx < NB) { boff[idx] = base; base += v[j]; }
    }
    if (t == 0) boff[NB] = NE;
}

// ---------- k4: deterministic bucket partition via LDS cursors ----------
__global__ __launch_bounds__(256) void partition_kernel(
    const int* __restrict__ ei, const float* __restrict__ ew,
    const int* __restrict__ H, const int* __restrict__ boff,
    uint2* __restrict__ part)
{
    __shared__ int cur[NB];
    int t = threadIdx.x;
    for (int i = t; i < NB; i += 256)
        cur[i] = boff[i] + H[blockIdx.x * NB + i];
    __syncthreads();
    int base = blockIdx.x * CHUNK_E;
    int end  = min(base + CHUNK_E, NE);
    for (int e = base + t; e < end; e += 256) {
        int s = ei[e], d = ei[NE + e];
        float w = ew[e];
        int b = d >> 6;
        int pos = atomicAdd(&cur[b], 1);   // LDS atomic, block-local
        // src fits in 16 bits (50000 < 65536); dloc in bits 16..21
        part[pos] = make_uint2((unsigned)s | ((unsigned)(d & 63) << 16),
                               __float_as_uint(w));
    }
}

// ---------- k5: per-bucket counting sort -> per-node CSR + csr_off ----------
__global__ __launch_bounds__(256) void bucketsort_kernel(
    const uint2* __restrict__ part, const int* __restrict__ boff,
    uint2* __restrict__ csr, int* __restrict__ csr_off)
{
    __shared__ int cnt[BK];
    __shared__ int cur[BK];
    int b = blockIdx.x, t = threadIdx.x;
    if (t < BK) cnt[t] = 0;
    __syncthreads();
    int s0 = boff[b], s1 = boff[b + 1];
    for (int e = s0 + t; e < s1; e += 256)
        atomicAdd(&cnt[part[e].x >> 16], 1);
    __syncthreads();
    if (t < BK) {
        int v = cnt[t];
        int inc = v;
#pragma unroll
        for (int o = 1; o < BK; o <<= 1) {
            int u = __shfl_up(inc, o, 64);
            if (t >= o) inc += u;
        }
        int ex = inc - v;               // exclusive prefix within bucket
        cur[t] = ex;
        csr_off[b * BK + t] = s0 + ex;
    }
    if (b == NB - 1 && t == 0) csr_off[NB * BK] = NE;
    __syncthreads();
    for (int e = s0 + t; e < s1; e += 256) {
        uint2 pk = part[e];
        int nl = pk.x >> 16;
        int pos = atomicAdd(&cur[nl], 1);
        csr[s0 + pos] = make_uint2(pk.x & 0xFFFFu, pk.y);  // (src, w)
    }
}

// ---------- k6: node-parallel aggregate + root + relu + pool ----------
#define UIF __uint_as_float
__global__ __launch_bounds__(256) void nodeagg_kernel(
    const float* __restrict__ y, const float* __restrict__ root,
    const int* __restrict__ csr_off, const uint2* __restrict__ csr,
    const int* __restrict__ batch, float* __restrict__ pooled)
{
    int n = blockIdx.x * 8 + (threadIdx.x >> 5);   // one 32-lane group per node
    int c = threadIdx.x & 31;
    if (n >= NN) return;
    float val = root[n * DIM + c];
    int e  = csr_off[n];
    int e1 = csr_off[n + 1];
    for (; e + 8 <= e1; e += 8) {
        // uniform-address loads within the group (broadcast), all independent
        uint2 a0 = csr[e],     a1 = csr[e + 1], a2 = csr[e + 2], a3 = csr[e + 3];
        uint2 a4 = csr[e + 4], a5 = csr[e + 5], a6 = csr[e + 6], a7 = csr[e + 7];
        float v0 = y[a0.x * DIM + c], v1 = y[a1.x * DIM + c];
        float v2 = y[a2.x * DIM + c], v3 = y[a3.x * DIM + c];
        float v4 = y[a4.x * DIM + c], v5 = y[a5.x * DIM + c];
        float v6 = y[a6.x * DIM + c], v7 = y[a7.x * DIM + c];
        val = fmaf(UIF(a0.y), v0, val); val = fmaf(UIF(a1.y), v1, val);
        val = fmaf(UIF(a2.y), v2, val); val = fmaf(UIF(a3.y), v3, val);
        val = fmaf(UIF(a4.y), v4, val); val = fmaf(UIF(a5.y), v5, val);
        val = fmaf(UIF(a6.y), v6, val); val = fmaf(UIF(a7.y), v7, val);
    }
    for (; e < e1; ++e) {
        uint2 a = csr[e];
        val = fmaf(UIF(a.y), y[a.x * DIM + c], val);
    }
    val = fmaxf(val, 0.0f);
    atomicAdd(&pooled[batch[n] * DIM + c], val);
}

// ---------- k7: MLP head + log_softmax ----------
__global__ __launch_bounds__(512) void head_kernel(
    const float* __restrict__ pooled, const float* __restrict__ w_fc1,
    const float* __restrict__ b_fc1, const float* __restrict__ w_fc2,
    const float* __restrict__ b_fc2, float* __restrict__ out)
{
    __shared__ float s_fc1[DIM * DIM];
    __shared__ float s_b1[DIM];
    __shared__ float s_fc2[DIM * 2];
    __shared__ float s_b2[2];
    int tid = threadIdx.x;
    s_fc1[tid]       = w_fc1[tid];
    s_fc1[tid + 512] = w_fc1[tid + 512];
    if (tid < DIM * 2) s_fc2[tid] = w_fc2[tid];
    if (tid < DIM)     s_b1[tid]  = b_fc1[tid];
    if (tid < 2)       s_b2[tid]  = b_fc2[tid];
    __syncthreads();

    int g = tid;
    if (g >= NG) return;
    const float* p = pooled + g * DIM;
    float h2[DIM];
#pragma unroll
    for (int c = 0; c < DIM; ++c) {
        float a = s_b1[c];
#pragma unroll
        for (int k = 0; k < DIM; ++k)
            a = fmaf(p[k], s_fc1[k * DIM + c], a);
        h2[c] = a > 0.0f ? a : 0.0f;
    }
    float l0 = s_b2[0], l1 = s_b2[1];
#pragma unroll
    for (int c = 0; c < DIM; ++c) {
        l0 = fmaf(h2[c], s_fc2[c * 2 + 0], l0);
        l1 = fmaf(h2[c], s_fc2[c * 2 + 1], l1);
    }
    float m   = fmaxf(l0, l1);
    float lse = m + logf(expf(l0 - m) + expf(l1 - m));
    out[g * 2 + 0] = l0 - lse;
    out[g * 2 + 1] = l1 - lse;
}

extern "C" void kernel_launch(void* const* d_in, const int* in_sizes, int n_in,
                              void* d_out, int out_size, void* d_ws, size_t ws_size,
                              hipStream_t stream) {
    const float* x      = (const float*)d_in[0];
    const float* ew     = (const float*)d_in[1];
    const float* w_rel  = (const float*)d_in[2];
    const float* b_rel  = (const float*)d_in[3];
    const float* w_root = (const float*)d_in[4];
    const float* w_fc1  = (const float*)d_in[5];
    const float* b_fc1  = (const float*)d_in[6];
    const float* w_fc2  = (const float*)d_in[7];
    const float* b_fc2  = (const float*)d_in[8];
    const int*   ei     = (const int*)d_in[9];
    const int*   batch  = (const int*)d_in[10];
    float* out = (float*)d_out;

    char* ws = (char*)d_ws;
    float* y       = (float*)ws;                               // 6.4 MB
    float* root    = y + (size_t)NN * DIM;                     // 6.4 MB
    uint2* part    = (uint2*)(root + (size_t)NN * DIM);        // 6.4 MB
    uint2* csr     = part + NE;                                // 6.4 MB
    int*   H       = (int*)(csr + NE);                         // HB*NB = 400 KB
    int*   colsum  = H + HB * NB;                              // NB
    int*   boff    = colsum + NB;                              // NB+1
    int*   csr_off = boff + NB + 2;                            // NB*BK+1 = 50049
    float* pooled  = (float*)(csr_off + NB * BK + 2);          // 64 KB

    hipMemsetAsync(pooled, 0, NG * DIM * sizeof(float), stream);

    proj_kernel<<<(NN + 31) / 32, 256, 0, stream>>>(x, w_rel, w_root, b_rel, y, root);
    histk<<<HB, 256, 0, stream>>>(ei, H);
    colscan<<<(NB + 255) / 256, 256, 0, stream>>>(H, colsum);
    bscan2<<<1, 256, 0, stream>>>(colsum, boff);
    partition_kernel<<<HB, 256, 0, stream>>>(ei, ew, H, boff, part);
    bucketsort_kernel<<<NB, 256, 0, stream>>>(part, boff, csr, csr_off);
    nodeagg_kernel<<<(NN + 7) / 8, 256, 0, stream>>>(y, root, csr_off, csr, batch, pooled);
    head_kernel<<<1, 512, 0, stream>>>(pooled, w_fc1, b_fc1, w_fc2, b_fc2, out);
}

// Round 7
// 132.352 us; speedup vs baseline: 2.0991x; 1.0222x over previous
//
#include <hip/hip_runtime.h>

#define NN 50000
#define NE 800000
#define NF 128
#define DIM 32
#define NG 500
#define BK 64                         // nodes per bucket
#define NB ((NN + BK - 1) / BK)       // 782 buckets
#define HB 128                        // histogram/partition blocks
#define CHUNK_E ((NE + HB - 1) / HB)  // 6250 edges per block
#define SC_CHUNK 4                    // 256*4 >= NB

// ---------- k1: y = x@w_rel ; root = x@w_root + b_rel ----------
// Register-blocked 4x4, no LDS. Block computes 64 rows x 64 cols (32 y | 32 root).
__global__ __launch_bounds__(256) void proj_kernel(
    const float* __restrict__ x, const float* __restrict__ w_rel,
    const float* __restrict__ w_root, const float* __restrict__ b_rel,
    float* __restrict__ y, float* __restrict__ root)
{
    int tid = threadIdx.x;
    int cg  = tid & 15;          // 16 col-groups x 4 cols = 64 cols
    int rg  = tid >> 4;          // 16 row-groups x 4 rows = 64 rows
    int c0  = cg * 4;
    int rb  = blockIdx.x * 64 + rg * 4;

    const float* Wp = (c0 < DIM) ? (w_rel + c0) : (w_root + (c0 - DIM));

    int r0s = min(rb + 0, NN - 1);
    int r1s = min(rb + 1, NN - 1);
    int r2s = min(rb + 2, NN - 1);
    int r3s = min(rb + 3, NN - 1);
    const float* x0 = x + (size_t)r0s * NF;
    const float* x1 = x + (size_t)r1s * NF;
    const float* x2 = x + (size_t)r2s * NF;
    const float* x3 = x + (size_t)r3s * NF;

    float4 a0 = {0,0,0,0}, a1 = {0,0,0,0}, a2 = {0,0,0,0}, a3 = {0,0,0,0};

#define F4FMA(acc, xv, wa, wb, wc, wd)                         \
    acc.x = fmaf(xv.x, wa.x, acc.x); acc.y = fmaf(xv.x, wa.y, acc.y); \
    acc.z = fmaf(xv.x, wa.z, acc.z); acc.w = fmaf(xv.x, wa.w, acc.w); \
    acc.x = fmaf(xv.y, wb.x, acc.x); acc.y = fmaf(xv.y, wb.y, acc.y); \
    acc.z = fmaf(xv.y, wb.z, acc.z); acc.w = fmaf(xv.y, wb.w, acc.w); \
    acc.x = fmaf(xv.z, wc.x, acc.x); acc.y = fmaf(xv.z, wc.y, acc.y); \
    acc.z = fmaf(xv.z, wc.z, acc.z); acc.w = fmaf(xv.z, wc.w, acc.w); \
    acc.x = fmaf(xv.w, wd.x, acc.x); acc.y = fmaf(xv.w, wd.y, acc.y); \
    acc.z = fmaf(xv.w, wd.z, acc.z); acc.w = fmaf(xv.w, wd.w, acc.w)

#pragma unroll 2
    for (int k = 0; k < NF; k += 4) {
        float4 wa = *reinterpret_cast<const float4*>(Wp + (k + 0) * DIM);
        float4 wb = *reinterpret_cast<const float4*>(Wp + (k + 1) * DIM);
        float4 wc = *reinterpret_cast<const float4*>(Wp + (k + 2) * DIM);
        float4 wd = *reinterpret_cast<const float4*>(Wp + (k + 3) * DIM);
        float4 xa = *reinterpret_cast<const float4*>(x0 + k);
        float4 xb = *reinterpret_cast<const float4*>(x1 + k);
        float4 xc = *reinterpret_cast<const float4*>(x2 + k);
        float4 xd = *reinterpret_cast<const float4*>(x3 + k);
        F4FMA(a0, xa, wa, wb, wc, wd);
        F4FMA(a1, xb, wa, wb, wc, wd);
        F4FMA(a2, xc, wa, wb, wc, wd);
        F4FMA(a3, xd, wa, wb, wc, wd);
    }
#undef F4FMA

    if (c0 < DIM) {
        if (rb + 0 < NN) *reinterpret_cast<float4*>(y + (size_t)(rb+0) * DIM + c0) = a0;
        if (rb + 1 < NN) *reinterpret_cast<float4*>(y + (size_t)(rb+1) * DIM + c0) = a1;
        if (rb + 2 < NN) *reinterpret_cast<float4*>(y + (size_t)(rb+2) * DIM + c0) = a2;
        if (rb + 3 < NN) *reinterpret_cast<float4*>(y + (size_t)(rb+3) * DIM + c0) = a3;
    } else {
        int cc = c0 - DIM;
        float4 bi = *reinterpret_cast<const float4*>(b_rel + cc);
        a0.x += bi.x; a0.y += bi.y; a0.z += bi.z; a0.w += bi.w;
        a1.x += bi.x; a1.y += bi.y; a1.z += bi.z; a1.w += bi.w;
        a2.x += bi.x; a2.y += bi.y; a2.z += bi.z; a2.w += bi.w;
        a3.x += bi.x; a3.y += bi.y; a3.z += bi.z; a3.w += bi.w;
        if (rb + 0 < NN) *reinterpret_cast<float4*>(root + (size_t)(rb+0) * DIM + cc) = a0;
        if (rb + 1 < NN) *reinterpret_cast<float4*>(root + (size_t)(rb+1) * DIM + cc) = a1;
        if (rb + 2 < NN) *reinterpret_cast<float4*>(root + (size_t)(rb+2) * DIM + cc) = a2;
        if (rb + 3 < NN) *reinterpret_cast<float4*>(root + (size_t)(rb+3) * DIM + cc) = a3;
    }
}

// ---------- k2: per-block bucket histogram (LDS) -> H[blk][bucket] ----------
__global__ __launch_bounds__(256) void histk(
    const int* __restrict__ ei, int* __restrict__ H)
{
    __shared__ int sh[NB];
    int t = threadIdx.x;
    for (int i = t; i < NB; i += 256) sh[i] = 0;
    __syncthreads();
    int base = blockIdx.x * CHUNK_E;
    int end  = min(base + CHUNK_E, NE);
    for (int e = base + t; e < end; e += 256)
        atomicAdd(&sh[ei[NE + e] >> 6], 1);
    __syncthreads();
    for (int i = t; i < NB; i += 256) H[blockIdx.x * NB + i] = sh[i];
}

// ---------- k3a: column prefix over the HB block rows ----------
__global__ __launch_bounds__(256) void colscan(
    int* __restrict__ H, int* __restrict__ colsum)
{
    int b = blockIdx.x * 256 + threadIdx.x;
    if (b >= NB) return;
    int run = 0;
#pragma unroll 8
    for (int blk = 0; blk < HB; ++blk) {
        int v = H[blk * NB + b];   // coalesced across threads
        H[blk * NB + b] = run;
        run += v;
    }
    colsum[b] = run;
}

// ---------- k3b: exclusive scan of colsum -> boff ----------
__global__ __launch_bounds__(256) void bscan2(
    const int* __restrict__ colsum, int* __restrict__ boff)
{
    __shared__ int s[256];
    int t = threadIdx.x;
    int v[SC_CHUNK];
    int sum = 0;
#pragma unroll
    for (int j = 0; j < SC_CHUNK; ++j) {
        int idx = t * SC_CHUNK + j;
        v[j] = (idx < NB) ? colsum[idx] : 0;
        sum += v[j];
    }
    s[t] = sum;
    __syncthreads();
    for (int o = 1; o < 256; o <<= 1) {
        int u = (t >= o) ? s[t - o] : 0;
        __syncthreads();
        s[t] += u;
        __syncthreads();
    }
    int base = s[t] - sum;
#pragma unroll
    for (int j = 0; j < SC_CHUNK; ++j) {
        int idx = t * SC_CHUNK + j;
        if (idx < NB) { boff[idx] = base; base += v[j]; }
    }
    if (t == 0) boff[NB] = NE;
}

// ---------- k4: deterministic bucket partition via LDS cursors ----------
__global__ __launch_bounds__(256) void partition_kernel(
    const int* __restrict__ ei, const float* __restrict__ ew,
    const int* __restrict__ H, const int* __restrict__ boff,
    uint2* __restrict__ part)
{
    __shared__ int cur[NB];
    int t = threadIdx.x;
    for (int i = t; i < NB; i += 256)
        cur[i] = boff[i] + H[blockIdx.x * NB + i];
    __syncthreads();
    int base = blockIdx.x * CHUNK_E;
    int end  = min(base + CHUNK_E, NE);
    for (int e = base + t; e < end; e += 256) {
        int s = ei[e], d = ei[NE + e];
        float w = ew[e];
        int b = d >> 6;
        int pos = atomicAdd(&cur[b], 1);   // LDS atomic, block-local
        part[pos] = make_uint2((unsigned)s | ((unsigned)(d & 63) << 16),
                               __float_as_uint(w));
    }
}

// ---------- k5: per-bucket counting sort -> per-node CSR + csr_off ----------
__global__ __launch_bounds__(256) void bucketsort_kernel(
    const uint2* __restrict__ part, const int* __restrict__ boff,
    uint2* __restrict__ csr, int* __restrict__ csr_off)
{
    __shared__ int cnt[BK];
    __shared__ int cur[BK];
    int b = blockIdx.x, t = threadIdx.x;
    if (t < BK) cnt[t] = 0;
    __syncthreads();
    int s0 = boff[b], s1 = boff[b + 1];
    for (int e = s0 + t; e < s1; e += 256)
        atomicAdd(&cnt[part[e].x >> 16], 1);
    __syncthreads();
    if (t < BK) {
        int v = cnt[t];
        int inc = v;
#pragma unroll
        for (int o = 1; o < BK; o <<= 1) {
            int u = __shfl_up(inc, o, 64);
            if (t >= o) inc += u;
        }
        int ex = inc - v;               // exclusive prefix within bucket
        cur[t] = ex;
        csr_off[b * BK + t] = s0 + ex;
    }
    if (b == NB - 1 && t == 0) csr_off[NB * BK] = NE;
    __syncthreads();
    for (int e = s0 + t; e < s1; e += 256) {
        uint2 pk = part[e];
        int nl = pk.x >> 16;
        int pos = atomicAdd(&cur[nl], 1);
        csr[s0 + pos] = make_uint2(pk.x & 0xFFFFu, pk.y);  // (src, w)
    }
}

// ---------- k6: node-parallel aggregate + root + relu + pool ----------
#define UIF __uint_as_float
__global__ __launch_bounds__(256) void nodeagg_kernel(
    const float* __restrict__ y, const float* __restrict__ root,
    const int* __restrict__ csr_off, const uint2* __restrict__ csr,
    const int* __restrict__ batch, float* __restrict__ pooled)
{
    int n = blockIdx.x * 8 + (threadIdx.x >> 5);   // one 32-lane group per node
    int c = threadIdx.x & 31;
    if (n >= NN) return;
    float val = root[n * DIM + c];
    int e  = csr_off[n];
    int e1 = csr_off[n + 1];
    for (; e + 8 <= e1; e += 8) {
        uint2 a0 = csr[e],     a1 = csr[e + 1], a2 = csr[e + 2], a3 = csr[e + 3];
        uint2 a4 = csr[e + 4], a5 = csr[e + 5], a6 = csr[e + 6], a7 = csr[e + 7];
        float v0 = y[a0.x * DIM + c], v1 = y[a1.x * DIM + c];
        float v2 = y[a2.x * DIM + c], v3 = y[a3.x * DIM + c];
        float v4 = y[a4.x * DIM + c], v5 = y[a5.x * DIM + c];
        float v6 = y[a6.x * DIM + c], v7 = y[a7.x * DIM + c];
        val = fmaf(UIF(a0.y), v0, val); val = fmaf(UIF(a1.y), v1, val);
        val = fmaf(UIF(a2.y), v2, val); val = fmaf(UIF(a3.y), v3, val);
        val = fmaf(UIF(a4.y), v4, val); val = fmaf(UIF(a5.y), v5, val);
        val = fmaf(UIF(a6.y), v6, val); val = fmaf(UIF(a7.y), v7, val);
    }
    for (; e < e1; ++e) {
        uint2 a = csr[e];
        val = fmaf(UIF(a.y), y[a.x * DIM + c], val);
    }
    val = fmaxf(val, 0.0f);
    atomicAdd(&pooled[batch[n] * DIM + c], val);
}

// ---------- k7: MLP head + log_softmax ----------
__global__ __launch_bounds__(512) void head_kernel(
    const float* __restrict__ pooled, const float* __restrict__ w_fc1,
    const float* __restrict__ b_fc1, const float* __restrict__ w_fc2,
    const float* __restrict__ b_fc2, float* __restrict__ out)
{
    __shared__ float s_fc1[DIM * DIM];
    __shared__ float s_b1[DIM];
    __shared__ float s_fc2[DIM * 2];
    __shared__ float s_b2[2];
    int tid = threadIdx.x;
    s_fc1[tid]       = w_fc1[tid];
    s_fc1[tid + 512] = w_fc1[tid + 512];
    if (tid < DIM * 2) s_fc2[tid] = w_fc2[tid];
    if (tid < DIM)     s_b1[tid]  = b_fc1[tid];
    if (tid < 2)       s_b2[tid]  = b_fc2[tid];
    __syncthreads();

    int g = tid;
    if (g >= NG) return;
    const float* p = pooled + g * DIM;
    float h2[DIM];
#pragma unroll
    for (int c = 0; c < DIM; ++c) {
        float a = s_b1[c];
#pragma unroll
        for (int k = 0; k < DIM; ++k)
            a = fmaf(p[k], s_fc1[k * DIM + c], a);
        h2[c] = a > 0.0f ? a : 0.0f;
    }
    float l0 = s_b2[0], l1 = s_b2[1];
#pragma unroll
    for (int c = 0; c < DIM; ++c) {
        l0 = fmaf(h2[c], s_fc2[c * 2 + 0], l0);
        l1 = fmaf(h2[c], s_fc2[c * 2 + 1], l1);
    }
    float m   = fmaxf(l0, l1);
    float lse = m + logf(expf(l0 - m) + expf(l1 - m));
    out[g * 2 + 0] = l0 - lse;
    out[g * 2 + 1] = l1 - lse;
}

extern "C" void kernel_launch(void* const* d_in, const int* in_sizes, int n_in,
                              void* d_out, int out_size, void* d_ws, size_t ws_size,
                              hipStream_t stream) {
    const float* x      = (const float*)d_in[0];
    const float* ew     = (const float*)d_in[1];
    const float* w_rel  = (const float*)d_in[2];
    const float* b_rel  = (const float*)d_in[3];
    const float* w_root = (const float*)d_in[4];
    const float* w_fc1  = (const float*)d_in[5];
    const float* b_fc1  = (const float*)d_in[6];
    const float* w_fc2  = (const float*)d_in[7];
    const float* b_fc2  = (const float*)d_in[8];
    const int*   ei     = (const int*)d_in[9];
    const int*   batch  = (const int*)d_in[10];
    float* out = (float*)d_out;

    char* ws = (char*)d_ws;
    float* y       = (float*)ws;                               // 6.4 MB
    float* root    = y + (size_t)NN * DIM;                     // 6.4 MB
    uint2* part    = (uint2*)(root + (size_t)NN * DIM);        // 6.4 MB
    uint2* csr     = part + NE;                                // 6.4 MB
    int*   H       = (int*)(csr + NE);                         // HB*NB = 400 KB
    int*   colsum  = H + HB * NB;                              // NB
    int*   boff    = colsum + NB;                              // NB+1
    int*   csr_off = boff + NB + 2;                            // NB*BK+1
    float* pooled  = (float*)(csr_off + NB * BK + 2);          // 64 KB

    hipMemsetAsync(pooled, 0, NG * DIM * sizeof(float), stream);

    proj_kernel<<<NB, 256, 0, stream>>>(x, w_rel, w_root, b_rel, y, root);
    histk<<<HB, 256, 0, stream>>>(ei, H);
    colscan<<<(NB + 255) / 256, 256, 0, stream>>>(H, colsum);
    bscan2<<<1, 256, 0, stream>>>(colsum, boff);
    partition_kernel<<<HB, 256, 0, stream>>>(ei, ew, H, boff, part);
    bucketsort_kernel<<<NB, 256, 0, stream>>>(part, boff, csr, csr_off);
    nodeagg_kernel<<<(NN + 7) / 8, 256, 0, stream>>>(y, root, csr_off, csr, batch, pooled);
    head_kernel<<<1, 512, 0, stream>>>(pooled, w_fc1, b_fc1, w_fc2, b_fc2, out);
}

// Round 8
// 112.903 us; speedup vs baseline: 2.4606x; 1.1723x over previous
//
#include <hip/hip_runtime.h>

#define NN 50000
#define NE 800000
#define NF 128
#define DIM 32
#define NG 500
#define BK 64                         // nodes per bucket
#define NB ((NN + BK - 1) / BK)       // 782 buckets
#define HB 128                        // histogram/partition blocks
#define CHUNK_E ((NE + HB - 1) / HB)  // 6250 edges per block
#define SC_CHUNK 4                    // 256*4 >= NB

// ---------- k1: y = x@w_rel ; root = x@w_root + b_rel ----------
// W staged in LDS; x pipelined from global; 4x4 register tile per thread.
__global__ __launch_bounds__(256) void proj_kernel(
    const float* __restrict__ x, const float* __restrict__ w_rel,
    const float* __restrict__ w_root, const float* __restrict__ b_rel,
    float* __restrict__ y, float* __restrict__ root)
{
    __shared__ float s_w[2 * NF * DIM];   // 32 KB: [0..4095]=w_rel, [4096..]=w_root
    int tid = threadIdx.x;
    {
        const float4* wr4 = reinterpret_cast<const float4*>(w_rel);
        const float4* wo4 = reinterpret_cast<const float4*>(w_root);
        float4* s4 = reinterpret_cast<float4*>(s_w);
#pragma unroll
        for (int j = 0; j < 4; ++j) s4[tid + j * 256]        = wr4[tid + j * 256];
#pragma unroll
        for (int j = 0; j < 4; ++j) s4[1024 + tid + j * 256] = wo4[tid + j * 256];
    }

    int cg = tid & 15;           // 16 col-groups x 4 cols = 64 virtual cols
    int rg = tid >> 4;           // 16 row-groups x 4 rows = 64 rows
    int c0 = cg * 4;
    int rb = blockIdx.x * 64 + rg * 4;

    const float* Wb = (c0 < DIM) ? (s_w + c0) : (s_w + NF * DIM + (c0 - DIM));

    int r0s = min(rb + 0, NN - 1);
    int r1s = min(rb + 1, NN - 1);
    int r2s = min(rb + 2, NN - 1);
    int r3s = min(rb + 3, NN - 1);
    const float* x0 = x + (size_t)r0s * NF;
    const float* x1 = x + (size_t)r1s * NF;
    const float* x2 = x + (size_t)r2s * NF;
    const float* x3 = x + (size_t)r3s * NF;

    __syncthreads();

    float4 a0 = {0,0,0,0}, a1 = {0,0,0,0}, a2 = {0,0,0,0}, a3 = {0,0,0,0};

#define F4FMA(acc, xv, wa, wb_, wc, wd)                                \
    acc.x = fmaf(xv.x, wa.x, acc.x);  acc.y = fmaf(xv.x, wa.y, acc.y); \
    acc.z = fmaf(xv.x, wa.z, acc.z);  acc.w = fmaf(xv.x, wa.w, acc.w); \
    acc.x = fmaf(xv.y, wb_.x, acc.x); acc.y = fmaf(xv.y, wb_.y, acc.y); \
    acc.z = fmaf(xv.y, wb_.z, acc.z); acc.w = fmaf(xv.y, wb_.w, acc.w); \
    acc.x = fmaf(xv.z, wc.x, acc.x);  acc.y = fmaf(xv.z, wc.y, acc.y); \
    acc.z = fmaf(xv.z, wc.z, acc.z);  acc.w = fmaf(xv.z, wc.w, acc.w); \
    acc.x = fmaf(xv.w, wd.x, acc.x);  acc.y = fmaf(xv.w, wd.y, acc.y); \
    acc.z = fmaf(xv.w, wd.z, acc.z);  acc.w = fmaf(xv.w, wd.w, acc.w)

    // software pipeline: x loads one 4-k step ahead
    float4 na = *reinterpret_cast<const float4*>(x0);
    float4 nb = *reinterpret_cast<const float4*>(x1);
    float4 nc = *reinterpret_cast<const float4*>(x2);
    float4 nd = *reinterpret_cast<const float4*>(x3);
#pragma unroll
    for (int k = 0; k < NF; k += 4) {
        float4 xa = na, xb = nb, xc = nc, xd = nd;
        if (k + 4 < NF) {
            na = *reinterpret_cast<const float4*>(x0 + k + 4);
            nb = *reinterpret_cast<const float4*>(x1 + k + 4);
            nc = *reinterpret_cast<const float4*>(x2 + k + 4);
            nd = *reinterpret_cast<const float4*>(x3 + k + 4);
        }
        float4 wa = *reinterpret_cast<const float4*>(Wb + (k + 0) * DIM);
        float4 wb2 = *reinterpret_cast<const float4*>(Wb + (k + 1) * DIM);
        float4 wc = *reinterpret_cast<const float4*>(Wb + (k + 2) * DIM);
        float4 wd = *reinterpret_cast<const float4*>(Wb + (k + 3) * DIM);
        F4FMA(a0, xa, wa, wb2, wc, wd);
        F4FMA(a1, xb, wa, wb2, wc, wd);
        F4FMA(a2, xc, wa, wb2, wc, wd);
        F4FMA(a3, xd, wa, wb2, wc, wd);
    }
#undef F4FMA

    if (c0 < DIM) {
        if (rb + 0 < NN) *reinterpret_cast<float4*>(y + (size_t)(rb+0) * DIM + c0) = a0;
        if (rb + 1 < NN) *reinterpret_cast<float4*>(y + (size_t)(rb+1) * DIM + c0) = a1;
        if (rb + 2 < NN) *reinterpret_cast<float4*>(y + (size_t)(rb+2) * DIM + c0) = a2;
        if (rb + 3 < NN) *reinterpret_cast<float4*>(y + (size_t)(rb+3) * DIM + c0) = a3;
    } else {
        int cc = c0 - DIM;
        float4 bi = *reinterpret_cast<const float4*>(b_rel + cc);
        a0.x += bi.x; a0.y += bi.y; a0.z += bi.z; a0.w += bi.w;
        a1.x += bi.x; a1.y += bi.y; a1.z += bi.z; a1.w += bi.w;
        a2.x += bi.x; a2.y += bi.y; a2.z += bi.z; a2.w += bi.w;
        a3.x += bi.x; a3.y += bi.y; a3.z += bi.z; a3.w += bi.w;
        if (rb + 0 < NN) *reinterpret_cast<float4*>(root + (size_t)(rb+0) * DIM + cc) = a0;
        if (rb + 1 < NN) *reinterpret_cast<float4*>(root + (size_t)(rb+1) * DIM + cc) = a1;
        if (rb + 2 < NN) *reinterpret_cast<float4*>(root + (size_t)(rb+2) * DIM + cc) = a2;
        if (rb + 3 < NN) *reinterpret_cast<float4*>(root + (size_t)(rb+3) * DIM + cc) = a3;
    }
}

// ---------- k2: per-block bucket histogram (LDS) + zero pooled ----------
__global__ __launch_bounds__(256) void histk(
    const int* __restrict__ ei, int* __restrict__ H, float* __restrict__ pooled)
{
    // zero pooled (replaces the 40us fillBuffer dispatch); nodeagg runs much later
    int pi = blockIdx.x * 256 + threadIdx.x;
    if (pi < NG * DIM) pooled[pi] = 0.0f;

    __shared__ int sh[NB];
    int t = threadIdx.x;
    for (int i = t; i < NB; i += 256) sh[i] = 0;
    __syncthreads();
    int base = blockIdx.x * CHUNK_E;
    int end  = min(base + CHUNK_E, NE);
    for (int e = base + t; e < end; e += 256)
        atomicAdd(&sh[ei[NE + e] >> 6], 1);
    __syncthreads();
    for (int i = t; i < NB; i += 256) H[blockIdx.x * NB + i] = sh[i];
}

// ---------- k3a: column prefix over the HB block rows ----------
__global__ __launch_bounds__(256) void colscan(
    int* __restrict__ H, int* __restrict__ colsum)
{
    int b = blockIdx.x * 256 + threadIdx.x;
    if (b >= NB) return;
    int run = 0;
#pragma unroll 8
    for (int blk = 0; blk < HB; ++blk) {
        int v = H[blk * NB + b];
        H[blk * NB + b] = run;
        run += v;
    }
    colsum[b] = run;
}

// ---------- k3b: exclusive scan of colsum -> boff ----------
__global__ __launch_bounds__(256) void bscan2(
    const int* __restrict__ colsum, int* __restrict__ boff)
{
    __shared__ int s[256];
    int t = threadIdx.x;
    int v[SC_CHUNK];
    int sum = 0;
#pragma unroll
    for (int j = 0; j < SC_CHUNK; ++j) {
        int idx = t * SC_CHUNK + j;
        v[j] = (idx < NB) ? colsum[idx] : 0;
        sum += v[j];
    }
    s[t] = sum;
    __syncthreads();
    for (int o = 1; o < 256; o <<= 1) {
        int u = (t >= o) ? s[t - o] : 0;
        __syncthreads();
        s[t] += u;
        __syncthreads();
    }
    int base = s[t] - sum;
#pragma unroll
    for (int j = 0; j < SC_CHUNK; ++j) {
        int idx = t * SC_CHUNK + j;
        if (idx < NB) { boff[idx] = base; base += v[j]; }
    }
    if (t == 0) boff[NB] = NE;
}

// ---------- k4: deterministic bucket partition via LDS cursors ----------
__global__ __launch_bounds__(256) void partition_kernel(
    const int* __restrict__ ei, const float* __restrict__ ew,
    const int* __restrict__ H, const int* __restrict__ boff,
    uint2* __restrict__ part)
{
    __shared__ int cur[NB];
    int t = threadIdx.x;
    for (int i = t; i < NB; i += 256)
        cur[i] = boff[i] + H[blockIdx.x * NB + i];
    __syncthreads();
    int base = blockIdx.x * CHUNK_E;
    int end  = min(base + CHUNK_E, NE);
    for (int e = base + t; e < end; e += 256) {
        int s = ei[e], d = ei[NE + e];
        float w = ew[e];
        int b = d >> 6;
        int pos = atomicAdd(&cur[b], 1);   // LDS atomic, block-local
        part[pos] = make_uint2((unsigned)s | ((unsigned)(d & 63) << 16),
                               __float_as_uint(w));
    }
}

// ---------- k5: per-bucket counting sort -> per-node CSR + csr_off ----------
__global__ __launch_bounds__(256) void bucketsort_kernel(
    const uint2* __restrict__ part, const int* __restrict__ boff,
    uint2* __restrict__ csr, int* __restrict__ csr_off)
{
    __shared__ int cnt[BK];
    __shared__ int cur[BK];
    int b = blockIdx.x, t = threadIdx.x;
    if (t < BK) cnt[t] = 0;
    __syncthreads();
    int s0 = boff[b], s1 = boff[b + 1];
    for (int e = s0 + t; e < s1; e += 256)
        atomicAdd(&cnt[part[e].x >> 16], 1);
    __syncthreads();
    if (t < BK) {
        int v = cnt[t];
        int inc = v;
#pragma unroll
        for (int o = 1; o < BK; o <<= 1) {
            int u = __shfl_up(inc, o, 64);
            if (t >= o) inc += u;
        }
        int ex = inc - v;
        cur[t] = ex;
        csr_off[b * BK + t] = s0 + ex;
    }
    if (b == NB - 1 && t == 0) csr_off[NB * BK] = NE;
    __syncthreads();
    for (int e = s0 + t; e < s1; e += 256) {
        uint2 pk = part[e];
        int nl = pk.x >> 16;
        int pos = atomicAdd(&cur[nl], 1);
        csr[s0 + pos] = make_uint2(pk.x & 0xFFFFu, pk.y);  // (src, w)
    }
}

// ---------- k6: node-parallel aggregate + root + relu + pool ----------
#define UIF __uint_as_float
__global__ __launch_bounds__(256) void nodeagg_kernel(
    const float* __restrict__ y, const float* __restrict__ root,
    const int* __restrict__ csr_off, const uint2* __restrict__ csr,
    const int* __restrict__ batch, float* __restrict__ pooled)
{
    int n = blockIdx.x * 8 + (threadIdx.x >> 5);   // one 32-lane group per node
    int c = threadIdx.x & 31;
    if (n >= NN) return;
    float val = root[n * DIM + c];
    int e  = csr_off[n];
    int e1 = csr_off[n + 1];
    for (; e + 8 <= e1; e += 8) {
        uint2 a0 = csr[e],     a1 = csr[e + 1], a2 = csr[e + 2], a3 = csr[e + 3];
        uint2 a4 = csr[e + 4], a5 = csr[e + 5], a6 = csr[e + 6], a7 = csr[e + 7];
        float v0 = y[a0.x * DIM + c], v1 = y[a1.x * DIM + c];
        float v2 = y[a2.x * DIM + c], v3 = y[a3.x * DIM + c];
        float v4 = y[a4.x * DIM + c], v5 = y[a5.x * DIM + c];
        float v6 = y[a6.x * DIM + c], v7 = y[a7.x * DIM + c];
        val = fmaf(UIF(a0.y), v0, val); val = fmaf(UIF(a1.y), v1, val);
        val = fmaf(UIF(a2.y), v2, val); val = fmaf(UIF(a3.y), v3, val);
        val = fmaf(UIF(a4.y), v4, val); val = fmaf(UIF(a5.y), v5, val);
        val = fmaf(UIF(a6.y), v6, val); val = fmaf(UIF(a7.y), v7, val);
    }
    for (; e < e1; ++e) {
        uint2 a = csr[e];
        val = fmaf(UIF(a.y), y[a.x * DIM + c], val);
    }
    val = fmaxf(val, 0.0f);
    atomicAdd(&pooled[batch[n] * DIM + c], val);
}

// ---------- k7: MLP head + log_softmax ----------
__global__ __launch_bounds__(512) void head_kernel(
    const float* __restrict__ pooled, const float* __restrict__ w_fc1,
    const float* __restrict__ b_fc1, const float* __restrict__ w_fc2,
    const float* __restrict__ b_fc2, float* __restrict__ out)
{
    __shared__ float s_fc1[DIM * DIM];
    __shared__ float s_b1[DIM];
    __shared__ float s_fc2[DIM * 2];
    __shared__ float s_b2[2];
    int tid = threadIdx.x;
    s_fc1[tid]       = w_fc1[tid];
    s_fc1[tid + 512] = w_fc1[tid + 512];
    if (tid < DIM * 2) s_fc2[tid] = w_fc2[tid];
    if (tid < DIM)     s_b1[tid]  = b_fc1[tid];
    if (tid < 2)       s_b2[tid]  = b_fc2[tid];
    __syncthreads();

    int g = tid;
    if (g >= NG) return;
    const float* p = pooled + g * DIM;
    float h2[DIM];
#pragma unroll
    for (int c = 0; c < DIM; ++c) {
        float a = s_b1[c];
#pragma unroll
        for (int k = 0; k < DIM; ++k)
            a = fmaf(p[k], s_fc1[k * DIM + c], a);
        h2[c] = a > 0.0f ? a : 0.0f;
    }
    float l0 = s_b2[0], l1 = s_b2[1];
#pragma unroll
    for (int c = 0; c < DIM; ++c) {
        l0 = fmaf(h2[c], s_fc2[c * 2 + 0], l0);
        l1 = fmaf(h2[c], s_fc2[c * 2 + 1], l1);
    }
    float m   = fmaxf(l0, l1);
    float lse = m + logf(expf(l0 - m) + expf(l1 - m));
    out[g * 2 + 0] = l0 - lse;
    out[g * 2 + 1] = l1 - lse;
}

extern "C" void kernel_launch(void* const* d_in, const int* in_sizes, int n_in,
                              void* d_out, int out_size, void* d_ws, size_t ws_size,
                              hipStream_t stream) {
    const float* x      = (const float*)d_in[0];
    const float* ew     = (const float*)d_in[1];
    const float* w_rel  = (const float*)d_in[2];
    const float* b_rel  = (const float*)d_in[3];
    const float* w_root = (const float*)d_in[4];
    const float* w_fc1  = (const float*)d_in[5];
    const float* b_fc1  = (const float*)d_in[6];
    const float* w_fc2  = (const float*)d_in[7];
    const float* b_fc2  = (const float*)d_in[8];
    const int*   ei     = (const int*)d_in[9];
    const int*   batch  = (const int*)d_in[10];
    float* out = (float*)d_out;

    char* ws = (char*)d_ws;
    float* y       = (float*)ws;                               // 6.4 MB
    float* root    = y + (size_t)NN * DIM;                     // 6.4 MB
    uint2* part    = (uint2*)(root + (size_t)NN * DIM);        // 6.4 MB
    uint2* csr     = part + NE;                                // 6.4 MB
    int*   H       = (int*)(csr + NE);                         // HB*NB = 400 KB
    int*   colsum  = H + HB * NB;                              // NB
    int*   boff    = colsum + NB;                              // NB+1
    int*   csr_off = boff + NB + 2;                            // NB*BK+1
    float* pooled  = (float*)(csr_off + NB * BK + 2);          // 64 KB

    proj_kernel<<<NB, 256, 0, stream>>>(x, w_rel, w_root, b_rel, y, root);
    histk<<<HB, 256, 0, stream>>>(ei, H, pooled);
    colscan<<<(NB + 255) / 256, 256, 0, stream>>>(H, colsum);
    bscan2<<<1, 256, 0, stream>>>(colsum, boff);
    partition_kernel<<<HB, 256, 0, stream>>>(ei, ew, H, boff, part);
    bucketsort_kernel<<<NB, 256, 0, stream>>>(part, boff, csr, csr_off);
    nodeagg_kernel<<<(NN + 7) / 8, 256, 0, stream>>>(y, root, csr_off, csr, batch, pooled);
    head_kernel<<<1, 512, 0, stream>>>(pooled, w_fc1, b_fc1, w_fc2, b_fc2, out);
}

// Round 9
// 110.742 us; speedup vs baseline: 2.5087x; 1.0195x over previous
//
#include <hip/hip_runtime.h>

#define NN 50000
#define NE 800000
#define NF 128
#define DIM 32
#define NG 500
#define BK 64                         // nodes per bucket
#define NB ((NN + BK - 1) / BK)       // 782 buckets
#define HB 256                        // histogram/partition blocks
#define CHUNK_E ((NE + HB - 1) / HB)  // 3125 edges per block
#define SC_CHUNK 4                    // 256*4 >= NB

// ---------- k1: y = x@w_rel ; root = x@w_root + b_rel ----------
// W staged in LDS; x pipelined from global; 4x4 register tile per thread.
__global__ __launch_bounds__(256) void proj_kernel(
    const float* __restrict__ x, const float* __restrict__ w_rel,
    const float* __restrict__ w_root, const float* __restrict__ b_rel,
    float* __restrict__ y, float* __restrict__ root)
{
    __shared__ float s_w[2 * NF * DIM];   // 32 KB
    int tid = threadIdx.x;
    {
        const float4* wr4 = reinterpret_cast<const float4*>(w_rel);
        const float4* wo4 = reinterpret_cast<const float4*>(w_root);
        float4* s4 = reinterpret_cast<float4*>(s_w);
#pragma unroll
        for (int j = 0; j < 4; ++j) s4[tid + j * 256]        = wr4[tid + j * 256];
#pragma unroll
        for (int j = 0; j < 4; ++j) s4[1024 + tid + j * 256] = wo4[tid + j * 256];
    }

    int cg = tid & 15;
    int rg = tid >> 4;
    int c0 = cg * 4;
    int rb = blockIdx.x * 64 + rg * 4;

    const float* Wb = (c0 < DIM) ? (s_w + c0) : (s_w + NF * DIM + (c0 - DIM));

    int r0s = min(rb + 0, NN - 1);
    int r1s = min(rb + 1, NN - 1);
    int r2s = min(rb + 2, NN - 1);
    int r3s = min(rb + 3, NN - 1);
    const float* x0 = x + (size_t)r0s * NF;
    const float* x1 = x + (size_t)r1s * NF;
    const float* x2 = x + (size_t)r2s * NF;
    const float* x3 = x + (size_t)r3s * NF;

    __syncthreads();

    float4 a0 = {0,0,0,0}, a1 = {0,0,0,0}, a2 = {0,0,0,0}, a3 = {0,0,0,0};

#define F4FMA(acc, xv, wa, wb_, wc, wd)                                \
    acc.x = fmaf(xv.x, wa.x, acc.x);  acc.y = fmaf(xv.x, wa.y, acc.y); \
    acc.z = fmaf(xv.x, wa.z, acc.z);  acc.w = fmaf(xv.x, wa.w, acc.w); \
    acc.x = fmaf(xv.y, wb_.x, acc.x); acc.y = fmaf(xv.y, wb_.y, acc.y); \
    acc.z = fmaf(xv.y, wb_.z, acc.z); acc.w = fmaf(xv.y, wb_.w, acc.w); \
    acc.x = fmaf(xv.z, wc.x, acc.x);  acc.y = fmaf(xv.z, wc.y, acc.y); \
    acc.z = fmaf(xv.z, wc.z, acc.z);  acc.w = fmaf(xv.z, wc.w, acc.w); \
    acc.x = fmaf(xv.w, wd.x, acc.x);  acc.y = fmaf(xv.w, wd.y, acc.y); \
    acc.z = fmaf(xv.w, wd.z, acc.z);  acc.w = fmaf(xv.w, wd.w, acc.w)

    float4 na = *reinterpret_cast<const float4*>(x0);
    float4 nb = *reinterpret_cast<const float4*>(x1);
    float4 nc = *reinterpret_cast<const float4*>(x2);
    float4 nd = *reinterpret_cast<const float4*>(x3);
#pragma unroll
    for (int k = 0; k < NF; k += 4) {
        float4 xa = na, xb = nb, xc = nc, xd = nd;
        if (k + 4 < NF) {
            na = *reinterpret_cast<const float4*>(x0 + k + 4);
            nb = *reinterpret_cast<const float4*>(x1 + k + 4);
            nc = *reinterpret_cast<const float4*>(x2 + k + 4);
            nd = *reinterpret_cast<const float4*>(x3 + k + 4);
        }
        float4 wa  = *reinterpret_cast<const float4*>(Wb + (k + 0) * DIM);
        float4 wb2 = *reinterpret_cast<const float4*>(Wb + (k + 1) * DIM);
        float4 wc  = *reinterpret_cast<const float4*>(Wb + (k + 2) * DIM);
        float4 wd  = *reinterpret_cast<const float4*>(Wb + (k + 3) * DIM);
        F4FMA(a0, xa, wa, wb2, wc, wd);
        F4FMA(a1, xb, wa, wb2, wc, wd);
        F4FMA(a2, xc, wa, wb2, wc, wd);
        F4FMA(a3, xd, wa, wb2, wc, wd);
    }
#undef F4FMA

    if (c0 < DIM) {
        if (rb + 0 < NN) *reinterpret_cast<float4*>(y + (size_t)(rb+0) * DIM + c0) = a0;
        if (rb + 1 < NN) *reinterpret_cast<float4*>(y + (size_t)(rb+1) * DIM + c0) = a1;
        if (rb + 2 < NN) *reinterpret_cast<float4*>(y + (size_t)(rb+2) * DIM + c0) = a2;
        if (rb + 3 < NN) *reinterpret_cast<float4*>(y + (size_t)(rb+3) * DIM + c0) = a3;
    } else {
        int cc = c0 - DIM;
        float4 bi = *reinterpret_cast<const float4*>(b_rel + cc);
        a0.x += bi.x; a0.y += bi.y; a0.z += bi.z; a0.w += bi.w;
        a1.x += bi.x; a1.y += bi.y; a1.z += bi.z; a1.w += bi.w;
        a2.x += bi.x; a2.y += bi.y; a2.z += bi.z; a2.w += bi.w;
        a3.x += bi.x; a3.y += bi.y; a3.z += bi.z; a3.w += bi.w;
        if (rb + 0 < NN) *reinterpret_cast<float4*>(root + (size_t)(rb+0) * DIM + cc) = a0;
        if (rb + 1 < NN) *reinterpret_cast<float4*>(root + (size_t)(rb+1) * DIM + cc) = a1;
        if (rb + 2 < NN) *reinterpret_cast<float4*>(root + (size_t)(rb+2) * DIM + cc) = a2;
        if (rb + 3 < NN) *reinterpret_cast<float4*>(root + (size_t)(rb+3) * DIM + cc) = a3;
    }
}

// ---------- k2: per-block bucket histogram (LDS) + zero pooled ----------
__global__ __launch_bounds__(256) void histk(
    const int* __restrict__ ei, int* __restrict__ H, float* __restrict__ pooled)
{
    int pi = blockIdx.x * 256 + threadIdx.x;
    if (pi < NG * DIM) pooled[pi] = 0.0f;

    __shared__ int sh[NB];
    int t = threadIdx.x;
    for (int i = t; i < NB; i += 256) sh[i] = 0;
    __syncthreads();
    int base = blockIdx.x * CHUNK_E;
    int end  = min(base + CHUNK_E, NE);
    for (int e = base + t; e < end; e += 256)
        atomicAdd(&sh[ei[NE + e] >> 6], 1);
    __syncthreads();
    for (int i = t; i < NB; i += 256) H[blockIdx.x * NB + i] = sh[i];
}

// ---------- k3a: column prefix over the HB block rows ----------
__global__ __launch_bounds__(256) void colscan(
    int* __restrict__ H, int* __restrict__ colsum)
{
    int b = blockIdx.x * 256 + threadIdx.x;
    if (b >= NB) return;
    int run = 0;
#pragma unroll 8
    for (int blk = 0; blk < HB; ++blk) {
        int v = H[blk * NB + b];
        H[blk * NB + b] = run;
        run += v;
    }
    colsum[b] = run;
}

// ---------- k3b: exclusive scan of colsum -> boff ----------
__global__ __launch_bounds__(256) void bscan2(
    const int* __restrict__ colsum, int* __restrict__ boff)
{
    __shared__ int s[256];
    int t = threadIdx.x;
    int v[SC_CHUNK];
    int sum = 0;
#pragma unroll
    for (int j = 0; j < SC_CHUNK; ++j) {
        int idx = t * SC_CHUNK + j;
        v[j] = (idx < NB) ? colsum[idx] : 0;
        sum += v[j];
    }
    s[t] = sum;
    __syncthreads();
    for (int o = 1; o < 256; o <<= 1) {
        int u = (t >= o) ? s[t - o] : 0;
        __syncthreads();
        s[t] += u;
        __syncthreads();
    }
    int base = s[t] - sum;
#pragma unroll
    for (int j = 0; j < SC_CHUNK; ++j) {
        int idx = t * SC_CHUNK + j;
        if (idx < NB) { boff[idx] = base; base += v[j]; }
    }
    if (t == 0) boff[NB] = NE;
}

// ---------- k4: deterministic bucket partition via LDS cursors ----------
__global__ __launch_bounds__(256) void partition_kernel(
    const int* __restrict__ ei, const float* __restrict__ ew,
    const int* __restrict__ H, const int* __restrict__ boff,
    uint2* __restrict__ part)
{
    __shared__ int cur[NB];
    int t = threadIdx.x;
    for (int i = t; i < NB; i += 256)
        cur[i] = boff[i] + H[blockIdx.x * NB + i];
    __syncthreads();
    int base = blockIdx.x * CHUNK_E;
    int end  = min(base + CHUNK_E, NE);
    for (int e = base + t; e < end; e += 256) {
        int s = ei[e], d = ei[NE + e];
        float w = ew[e];
        int b = d >> 6;
        int pos = atomicAdd(&cur[b], 1);   // LDS atomic, block-local
        part[pos] = make_uint2((unsigned)s | ((unsigned)(d & 63) << 16),
                               __float_as_uint(w));
    }
}

// ---------- k5: per-bucket counting sort -> per-node CSR + csr_off ----------
__global__ __launch_bounds__(256) void bucketsort_kernel(
    const uint2* __restrict__ part, const int* __restrict__ boff,
    uint2* __restrict__ csr, int* __restrict__ csr_off)
{
    __shared__ int cnt[BK];
    __shared__ int cur[BK];
    int b = blockIdx.x, t = threadIdx.x;
    if (t < BK) cnt[t] = 0;
    __syncthreads();
    int s0 = boff[b], s1 = boff[b + 1];
    for (int e = s0 + t; e < s1; e += 256)
        atomicAdd(&cnt[part[e].x >> 16], 1);
    __syncthreads();
    if (t < BK) {
        int v = cnt[t];
        int inc = v;
#pragma unroll
        for (int o = 1; o < BK; o <<= 1) {
            int u = __shfl_up(inc, o, 64);
            if (t >= o) inc += u;
        }
        int ex = inc - v;
        cur[t] = ex;
        csr_off[b * BK + t] = s0 + ex;
    }
    if (b == NB - 1 && t == 0) csr_off[NB * BK] = NE;
    __syncthreads();
    for (int e = s0 + t; e < s1; e += 256) {
        uint2 pk = part[e];
        int nl = pk.x >> 16;
        int pos = atomicAdd(&cur[nl], 1);
        csr[s0 + pos] = make_uint2(pk.x & 0xFFFFu, pk.y);  // (src, w)
    }
}

// ---------- k6: one wave64 per node, 2-way edge-parallel halves ----------
#define UIF __uint_as_float
__global__ __launch_bounds__(256) void nodeagg_kernel(
    const float* __restrict__ y, const float* __restrict__ root,
    const int* __restrict__ csr_off, const uint2* __restrict__ csr,
    const int* __restrict__ batch, float* __restrict__ pooled)
{
    __shared__ float s_p[4][DIM];
    __shared__ int   s_g[4];
    int t    = threadIdx.x;
    int w    = t >> 6;                    // wave id 0..3
    int lane = t & 63;
    int half = lane >> 5;                 // 0: even edges, 1: odd edges
    int c    = lane & 31;
    int n    = blockIdx.x * 4 + w;        // NN % 4 == 0, always valid

    float val = half ? 0.0f : root[n * DIM + c];
    int e1 = csr_off[n + 1];
    int e  = csr_off[n] + half;
    for (; e + 14 < e1; e += 16) {        // 8 edges per half, csr[e..e+15] = one line
        uint2 a0 = csr[e],      a1 = csr[e + 2],  a2 = csr[e + 4],  a3 = csr[e + 6];
        uint2 a4 = csr[e + 8],  a5 = csr[e + 10], a6 = csr[e + 12], a7 = csr[e + 14];
        float v0 = y[a0.x * DIM + c], v1 = y[a1.x * DIM + c];
        float v2 = y[a2.x * DIM + c], v3 = y[a3.x * DIM + c];
        float v4 = y[a4.x * DIM + c], v5 = y[a5.x * DIM + c];
        float v6 = y[a6.x * DIM + c], v7 = y[a7.x * DIM + c];
        val = fmaf(UIF(a0.y), v0, val); val = fmaf(UIF(a1.y), v1, val);
        val = fmaf(UIF(a2.y), v2, val); val = fmaf(UIF(a3.y), v3, val);
        val = fmaf(UIF(a4.y), v4, val); val = fmaf(UIF(a5.y), v5, val);
        val = fmaf(UIF(a6.y), v6, val); val = fmaf(UIF(a7.y), v7, val);
    }
    for (; e < e1; e += 2) {
        uint2 a = csr[e];
        val = fmaf(UIF(a.y), y[a.x * DIM + c], val);
    }
    val += __shfl_xor(val, 32, 64);       // combine halves
    val = fmaxf(val, 0.0f);               // relu on full aggregate
    if (half == 0) {
        s_p[w][c] = val;
        if (c == 0) s_g[w] = batch[n];
    }
    __syncthreads();
    // wave 0 combines the block's 4 consecutive nodes (batch sorted -> mostly 1 graph)
    if (t < DIM) {
        int curg = s_g[0];
        float run = s_p[0][t];
#pragma unroll
        for (int j = 1; j < 4; ++j) {
            int g = s_g[j];
            float v = s_p[j][t];
            if (g != curg) {
                atomicAdd(&pooled[curg * DIM + t], run);
                curg = g; run = v;
            } else run += v;
        }
        atomicAdd(&pooled[curg * DIM + t], run);
    }
}

// ---------- k7: MLP head + log_softmax ----------
__global__ __launch_bounds__(512) void head_kernel(
    const float* __restrict__ pooled, const float* __restrict__ w_fc1,
    const float* __restrict__ b_fc1, const float* __restrict__ w_fc2,
    const float* __restrict__ b_fc2, float* __restrict__ out)
{
    __shared__ float s_fc1[DIM * DIM];
    __shared__ float s_b1[DIM];
    __shared__ float s_fc2[DIM * 2];
    __shared__ float s_b2[2];
    int tid = threadIdx.x;
    s_fc1[tid]       = w_fc1[tid];
    s_fc1[tid + 512] = w_fc1[tid + 512];
    if (tid < DIM * 2) s_fc2[tid] = w_fc2[tid];
    if (tid < DIM)     s_b1[tid]  = b_fc1[tid];
    if (tid < 2)       s_b2[tid]  = b_fc2[tid];
    __syncthreads();

    int g = tid;
    if (g >= NG) return;
    const float* p = pooled + g * DIM;
    float h2[DIM];
#pragma unroll
    for (int c = 0; c < DIM; ++c) {
        float a = s_b1[c];
#pragma unroll
        for (int k = 0; k < DIM; ++k)
            a = fmaf(p[k], s_fc1[k * DIM + c], a);
        h2[c] = a > 0.0f ? a : 0.0f;
    }
    float l0 = s_b2[0], l1 = s_b2[1];
#pragma unroll
    for (int c = 0; c < DIM; ++c) {
        l0 = fmaf(h2[c], s_fc2[c * 2 + 0], l0);
        l1 = fmaf(h2[c], s_fc2[c * 2 + 1], l1);
    }
    float m   = fmaxf(l0, l1);
    float lse = m + logf(expf(l0 - m) + expf(l1 - m));
    out[g * 2 + 0] = l0 - lse;
    out[g * 2 + 1] = l1 - lse;
}

extern "C" void kernel_launch(void* const* d_in, const int* in_sizes, int n_in,
                              void* d_out, int out_size, void* d_ws, size_t ws_size,
                              hipStream_t stream) {
    const float* x      = (const float*)d_in[0];
    const float* ew     = (const float*)d_in[1];
    const float* w_rel  = (const float*)d_in[2];
    const float* b_rel  = (const float*)d_in[3];
    const float* w_root = (const float*)d_in[4];
    const float* w_fc1  = (const float*)d_in[5];
    const float* b_fc1  = (const float*)d_in[6];
    const float* w_fc2  = (const float*)d_in[7];
    const float* b_fc2  = (const float*)d_in[8];
    const int*   ei     = (const int*)d_in[9];
    const int*   batch  = (const int*)d_in[10];
    float* out = (float*)d_out;

    char* ws = (char*)d_ws;
    float* y       = (float*)ws;                               // 6.4 MB
    float* root    = y + (size_t)NN * DIM;                     // 6.4 MB
    uint2* part    = (uint2*)(root + (size_t)NN * DIM);        // 6.4 MB
    uint2* csr     = part + NE;                                // 6.4 MB
    int*   H       = (int*)(csr + NE);                         // HB*NB = 800 KB
    int*   colsum  = H + HB * NB;                              // NB
    int*   boff    = colsum + NB;                              // NB+1
    int*   csr_off = boff + NB + 2;                            // NB*BK+1
    float* pooled  = (float*)(csr_off + NB * BK + 2);          // 64 KB

    proj_kernel<<<NB, 256, 0, stream>>>(x, w_rel, w_root, b_rel, y, root);
    histk<<<HB, 256, 0, stream>>>(ei, H, pooled);
    colscan<<<(NB + 255) / 256, 256, 0, stream>>>(H, colsum);
    bscan2<<<1, 256, 0, stream>>>(colsum, boff);
    partition_kernel<<<HB, 256, 0, stream>>>(ei, ew, H, boff, part);
    bucketsort_kernel<<<NB, 256, 0, stream>>>(part, boff, csr, csr_off);
    nodeagg_kernel<<<NN / 4, 256, 0, stream>>>(y, root, csr_off, csr, batch, pooled);
    head_kernel<<<1, 512, 0, stream>>>(pooled, w_fc1, b_fc1, w_fc2, b_fc2, out);
}

// Round 10
// 104.870 us; speedup vs baseline: 2.6491x; 1.0560x over previous
//
#include <hip/hip_runtime.h>

#define NN 50000
#define NE 800000
#define NF 128
#define DIM 32
#define NG 500
#define BK 64                         // nodes per bucket
#define NB ((NN + BK - 1) / BK)       // 782 buckets
#define HB 256                        // histogram/partition blocks
#define CHUNK_E ((NE + HB - 1) / HB)  // 3125 edges per block
#define SC_CHUNK 4                    // 256*4 >= NB

__device__ __forceinline__ unsigned rne16(float f) {
    unsigned u = __float_as_uint(f);
    return (u + 0x7FFFu + ((u >> 16) & 1u)) >> 16;   // bf16 round-to-nearest-even
}

// ---------- k1: yp = pack_bf16(x@w_rel) ; root = x@w_root + b_rel ----------
__global__ __launch_bounds__(256) void proj_kernel(
    const float* __restrict__ x, const float* __restrict__ w_rel,
    const float* __restrict__ w_root, const float* __restrict__ b_rel,
    unsigned* __restrict__ yp, float* __restrict__ root)
{
    __shared__ float s_w[2 * NF * DIM];   // 32 KB
    int tid = threadIdx.x;
    {
        const float4* wr4 = reinterpret_cast<const float4*>(w_rel);
        const float4* wo4 = reinterpret_cast<const float4*>(w_root);
        float4* s4 = reinterpret_cast<float4*>(s_w);
#pragma unroll
        for (int j = 0; j < 4; ++j) s4[tid + j * 256]        = wr4[tid + j * 256];
#pragma unroll
        for (int j = 0; j < 4; ++j) s4[1024 + tid + j * 256] = wo4[tid + j * 256];
    }

    int cg = tid & 15;
    int rg = tid >> 4;
    int c0 = cg * 4;
    int rb = blockIdx.x * 64 + rg * 4;

    const float* Wb = (c0 < DIM) ? (s_w + c0) : (s_w + NF * DIM + (c0 - DIM));

    int r0s = min(rb + 0, NN - 1);
    int r1s = min(rb + 1, NN - 1);
    int r2s = min(rb + 2, NN - 1);
    int r3s = min(rb + 3, NN - 1);
    const float* x0 = x + (size_t)r0s * NF;
    const float* x1 = x + (size_t)r1s * NF;
    const float* x2 = x + (size_t)r2s * NF;
    const float* x3 = x + (size_t)r3s * NF;

    __syncthreads();

    float4 a0 = {0,0,0,0}, a1 = {0,0,0,0}, a2 = {0,0,0,0}, a3 = {0,0,0,0};

#define F4FMA(acc, xv, wa, wb_, wc, wd)                                \
    acc.x = fmaf(xv.x, wa.x, acc.x);  acc.y = fmaf(xv.x, wa.y, acc.y); \
    acc.z = fmaf(xv.x, wa.z, acc.z);  acc.w = fmaf(xv.x, wa.w, acc.w); \
    acc.x = fmaf(xv.y, wb_.x, acc.x); acc.y = fmaf(xv.y, wb_.y, acc.y); \
    acc.z = fmaf(xv.y, wb_.z, acc.z); acc.w = fmaf(xv.y, wb_.w, acc.w); \
    acc.x = fmaf(xv.z, wc.x, acc.x);  acc.y = fmaf(xv.z, wc.y, acc.y); \
    acc.z = fmaf(xv.z, wc.z, acc.z);  acc.w = fmaf(xv.z, wc.w, acc.w); \
    acc.x = fmaf(xv.w, wd.x, acc.x);  acc.y = fmaf(xv.w, wd.y, acc.y); \
    acc.z = fmaf(xv.w, wd.z, acc.z);  acc.w = fmaf(xv.w, wd.w, acc.w)

    float4 na = *reinterpret_cast<const float4*>(x0);
    float4 nb = *reinterpret_cast<const float4*>(x1);
    float4 nc = *reinterpret_cast<const float4*>(x2);
    float4 nd = *reinterpret_cast<const float4*>(x3);
#pragma unroll
    for (int k = 0; k < NF; k += 4) {
        float4 xa = na, xb = nb, xc = nc, xd = nd;
        if (k + 4 < NF) {
            na = *reinterpret_cast<const float4*>(x0 + k + 4);
            nb = *reinterpret_cast<const float4*>(x1 + k + 4);
            nc = *reinterpret_cast<const float4*>(x2 + k + 4);
            nd = *reinterpret_cast<const float4*>(x3 + k + 4);
        }
        float4 wa  = *reinterpret_cast<const float4*>(Wb + (k + 0) * DIM);
        float4 wb2 = *reinterpret_cast<const float4*>(Wb + (k + 1) * DIM);
        float4 wc  = *reinterpret_cast<const float4*>(Wb + (k + 2) * DIM);
        float4 wd  = *reinterpret_cast<const float4*>(Wb + (k + 3) * DIM);
        F4FMA(a0, xa, wa, wb2, wc, wd);
        F4FMA(a1, xb, wa, wb2, wc, wd);
        F4FMA(a2, xc, wa, wb2, wc, wd);
        F4FMA(a3, xd, wa, wb2, wc, wd);
    }
#undef F4FMA

    if (c0 < DIM) {
        // pack 4 cols -> uint2 of bf16x2 at col-pair offset c0/2
        int cp0 = c0 >> 1;
#define PACK2(v) make_uint2(rne16(v.x) | (rne16(v.y) << 16), rne16(v.z) | (rne16(v.w) << 16))
        if (rb + 0 < NN) *reinterpret_cast<uint2*>(yp + (size_t)(rb+0) * 16 + cp0) = PACK2(a0);
        if (rb + 1 < NN) *reinterpret_cast<uint2*>(yp + (size_t)(rb+1) * 16 + cp0) = PACK2(a1);
        if (rb + 2 < NN) *reinterpret_cast<uint2*>(yp + (size_t)(rb+2) * 16 + cp0) = PACK2(a2);
        if (rb + 3 < NN) *reinterpret_cast<uint2*>(yp + (size_t)(rb+3) * 16 + cp0) = PACK2(a3);
#undef PACK2
    } else {
        int cc = c0 - DIM;
        float4 bi = *reinterpret_cast<const float4*>(b_rel + cc);
        a0.x += bi.x; a0.y += bi.y; a0.z += bi.z; a0.w += bi.w;
        a1.x += bi.x; a1.y += bi.y; a1.z += bi.z; a1.w += bi.w;
        a2.x += bi.x; a2.y += bi.y; a2.z += bi.z; a2.w += bi.w;
        a3.x += bi.x; a3.y += bi.y; a3.z += bi.z; a3.w += bi.w;
        if (rb + 0 < NN) *reinterpret_cast<float4*>(root + (size_t)(rb+0) * DIM + cc) = a0;
        if (rb + 1 < NN) *reinterpret_cast<float4*>(root + (size_t)(rb+1) * DIM + cc) = a1;
        if (rb + 2 < NN) *reinterpret_cast<float4*>(root + (size_t)(rb+2) * DIM + cc) = a2;
        if (rb + 3 < NN) *reinterpret_cast<float4*>(root + (size_t)(rb+3) * DIM + cc) = a3;
    }
}

// ---------- k2: per-block bucket histogram (LDS) + zero pooled ----------
__global__ __launch_bounds__(256) void histk(
    const int* __restrict__ ei, int* __restrict__ H, float* __restrict__ pooled)
{
    int pi = blockIdx.x * 256 + threadIdx.x;
    if (pi < NG * DIM) pooled[pi] = 0.0f;

    __shared__ int sh[NB];
    int t = threadIdx.x;
    for (int i = t; i < NB; i += 256) sh[i] = 0;
    __syncthreads();
    int base = blockIdx.x * CHUNK_E;
    int end  = min(base + CHUNK_E, NE);
    for (int e = base + t; e < end; e += 256)
        atomicAdd(&sh[ei[NE + e] >> 6], 1);
    __syncthreads();
    for (int i = t; i < NB; i += 256) H[blockIdx.x * NB + i] = sh[i];
}

// ---------- k3a: column prefix over the HB block rows ----------
__global__ __launch_bounds__(256) void colscan(
    int* __restrict__ H, int* __restrict__ colsum)
{
    int b = blockIdx.x * 256 + threadIdx.x;
    if (b >= NB) return;
    int run = 0;
#pragma unroll 8
    for (int blk = 0; blk < HB; ++blk) {
        int v = H[blk * NB + b];
        H[blk * NB + b] = run;
        run += v;
    }
    colsum[b] = run;
}

// ---------- k3b: exclusive scan of colsum -> boff ----------
__global__ __launch_bounds__(256) void bscan2(
    const int* __restrict__ colsum, int* __restrict__ boff)
{
    __shared__ int s[256];
    int t = threadIdx.x;
    int v[SC_CHUNK];
    int sum = 0;
#pragma unroll
    for (int j = 0; j < SC_CHUNK; ++j) {
        int idx = t * SC_CHUNK + j;
        v[j] = (idx < NB) ? colsum[idx] : 0;
        sum += v[j];
    }
    s[t] = sum;
    __syncthreads();
    for (int o = 1; o < 256; o <<= 1) {
        int u = (t >= o) ? s[t - o] : 0;
        __syncthreads();
        s[t] += u;
        __syncthreads();
    }
    int base = s[t] - sum;
#pragma unroll
    for (int j = 0; j < SC_CHUNK; ++j) {
        int idx = t * SC_CHUNK + j;
        if (idx < NB) { boff[idx] = base; base += v[j]; }
    }
    if (t == 0) boff[NB] = NE;
}

// ---------- k4: deterministic bucket partition via LDS cursors ----------
__global__ __launch_bounds__(256) void partition_kernel(
    const int* __restrict__ ei, const float* __restrict__ ew,
    const int* __restrict__ H, const int* __restrict__ boff,
    uint2* __restrict__ part)
{
    __shared__ int cur[NB];
    int t = threadIdx.x;
    for (int i = t; i < NB; i += 256)
        cur[i] = boff[i] + H[blockIdx.x * NB + i];
    __syncthreads();
    int base = blockIdx.x * CHUNK_E;
    int end  = min(base + CHUNK_E, NE);
    for (int e = base + t; e < end; e += 256) {
        int s = ei[e], d = ei[NE + e];
        float w = ew[e];
        int b = d >> 6;
        int pos = atomicAdd(&cur[b], 1);   // LDS atomic, block-local
        part[pos] = make_uint2((unsigned)s | ((unsigned)(d & 63) << 16),
                               __float_as_uint(w));
    }
}

// ---------- k5: per-bucket counting sort -> per-node CSR + csr_off ----------
__global__ __launch_bounds__(256) void bucketsort_kernel(
    const uint2* __restrict__ part, const int* __restrict__ boff,
    uint2* __restrict__ csr, int* __restrict__ csr_off)
{
    __shared__ int cnt[BK];
    __shared__ int cur[BK];
    int b = blockIdx.x, t = threadIdx.x;
    if (t < BK) cnt[t] = 0;
    __syncthreads();
    int s0 = boff[b], s1 = boff[b + 1];
    for (int e = s0 + t; e < s1; e += 256)
        atomicAdd(&cnt[part[e].x >> 16], 1);
    __syncthreads();
    if (t < BK) {
        int v = cnt[t];
        int inc = v;
#pragma unroll
        for (int o = 1; o < BK; o <<= 1) {
            int u = __shfl_up(inc, o, 64);
            if (t >= o) inc += u;
        }
        int ex = inc - v;
        cur[t] = ex;
        csr_off[b * BK + t] = s0 + ex;
    }
    if (b == NB - 1 && t == 0) csr_off[NB * BK] = NE;
    __syncthreads();
    for (int e = s0 + t; e < s1; e += 256) {
        uint2 pk = part[e];
        int nl = pk.x >> 16;
        int pos = atomicAdd(&cur[nl], 1);
        csr[s0 + pos] = make_uint2(pk.x & 0xFFFFu, pk.y);  // (src, w fp32)
    }
}

// ---------- k6: wave64/node, 4 edge slots x 16 col-pair lanes, bf16x2 y ----------
#define UIF __uint_as_float
__device__ __forceinline__ float blo(unsigned p) { return UIF(p << 16); }
__device__ __forceinline__ float bhi(unsigned p) { return UIF(p & 0xFFFF0000u); }

__global__ __launch_bounds__(256) void nodeagg_kernel(
    const unsigned* __restrict__ yp, const float* __restrict__ root,
    const int* __restrict__ csr_off, const uint2* __restrict__ csr,
    const int* __restrict__ batch, float* __restrict__ pooled)
{
    __shared__ float s_p[4][DIM];
    __shared__ int   s_g[4];
    int t    = threadIdx.x;
    int w    = t >> 6;                    // wave id 0..3
    int lane = t & 63;
    int q    = lane >> 4;                 // edge slot 0..3
    int cp   = lane & 15;                 // col pair -> cols (2cp, 2cp+1)
    int n    = blockIdx.x * 4 + w;        // NN % 4 == 0

    float v0 = 0.0f, v1 = 0.0f;
    int e1 = csr_off[n + 1];
    int e  = csr_off[n] + q;
    for (; e + 12 < e1; e += 16) {        // 16 edges per round (4 per slot)
        uint2 a0 = csr[e], a1 = csr[e + 4], a2 = csr[e + 8], a3 = csr[e + 12];
        unsigned p0 = yp[a0.x * 16 + cp];
        unsigned p1 = yp[a1.x * 16 + cp];
        unsigned p2 = yp[a2.x * 16 + cp];
        unsigned p3 = yp[a3.x * 16 + cp];
        float w0 = UIF(a0.y), w1 = UIF(a1.y), w2 = UIF(a2.y), w3 = UIF(a3.y);
        v0 = fmaf(w0, blo(p0), v0); v1 = fmaf(w0, bhi(p0), v1);
        v0 = fmaf(w1, blo(p1), v0); v1 = fmaf(w1, bhi(p1), v1);
        v0 = fmaf(w2, blo(p2), v0); v1 = fmaf(w2, bhi(p2), v1);
        v0 = fmaf(w3, blo(p3), v0); v1 = fmaf(w3, bhi(p3), v1);
    }
    for (; e < e1; e += 4) {
        uint2 a = csr[e];
        unsigned p = yp[a.x * 16 + cp];
        float ww = UIF(a.y);
        v0 = fmaf(ww, blo(p), v0); v1 = fmaf(ww, bhi(p), v1);
    }
    // combine the 4 edge slots
    v0 += __shfl_xor(v0, 16, 64); v0 += __shfl_xor(v0, 32, 64);
    v1 += __shfl_xor(v1, 16, 64); v1 += __shfl_xor(v1, 32, 64);

    if (q == 0) {                          // lanes 0..15 finalize
        float2 r = *reinterpret_cast<const float2*>(root + (size_t)n * DIM + 2 * cp);
        s_p[w][2 * cp]     = fmaxf(v0 + r.x, 0.0f);
        s_p[w][2 * cp + 1] = fmaxf(v1 + r.y, 0.0f);
        if (cp == 0) s_g[w] = batch[n];
    }
    __syncthreads();
    // combine the block's 4 consecutive nodes (batch sorted -> mostly same graph)
    if (t < DIM) {
        int curg = s_g[0];
        float run = s_p[0][t];
#pragma unroll
        for (int j = 1; j < 4; ++j) {
            int g = s_g[j];
            float v = s_p[j][t];
            if (g != curg) {
                atomicAdd(&pooled[curg * DIM + t], run);
                curg = g; run = v;
            } else run += v;
        }
        atomicAdd(&pooled[curg * DIM + t], run);
    }
}

// ---------- k7: MLP head + log_softmax ----------
__global__ __launch_bounds__(512) void head_kernel(
    const float* __restrict__ pooled, const float* __restrict__ w_fc1,
    const float* __restrict__ b_fc1, const float* __restrict__ w_fc2,
    const float* __restrict__ b_fc2, float* __restrict__ out)
{
    __shared__ float s_fc1[DIM * DIM];
    __shared__ float s_b1[DIM];
    __shared__ float s_fc2[DIM * 2];
    __shared__ float s_b2[2];
    int tid = threadIdx.x;
    s_fc1[tid]       = w_fc1[tid];
    s_fc1[tid + 512] = w_fc1[tid + 512];
    if (tid < DIM * 2) s_fc2[tid] = w_fc2[tid];
    if (tid < DIM)     s_b1[tid]  = b_fc1[tid];
    if (tid < 2)       s_b2[tid]  = b_fc2[tid];
    __syncthreads();

    int g = tid;
    if (g >= NG) return;
    const float* p = pooled + g * DIM;
    float h2[DIM];
#pragma unroll
    for (int c = 0; c < DIM; ++c) {
        float a = s_b1[c];
#pragma unroll
        for (int k = 0; k < DIM; ++k)
            a = fmaf(p[k], s_fc1[k * DIM + c], a);
        h2[c] = a > 0.0f ? a : 0.0f;
    }
    float l0 = s_b2[0], l1 = s_b2[1];
#pragma unroll
    for (int c = 0; c < DIM; ++c) {
        l0 = fmaf(h2[c], s_fc2[c * 2 + 0], l0);
        l1 = fmaf(h2[c], s_fc2[c * 2 + 1], l1);
    }
    float m   = fmaxf(l0, l1);
    float lse = m + logf(expf(l0 - m) + expf(l1 - m));
    out[g * 2 + 0] = l0 - lse;
    out[g * 2 + 1] = l1 - lse;
}

extern "C" void kernel_launch(void* const* d_in, const int* in_sizes, int n_in,
                              void* d_out, int out_size, void* d_ws, size_t ws_size,
                              hipStream_t stream) {
    const float* x      = (const float*)d_in[0];
    const float* ew     = (const float*)d_in[1];
    const float* w_rel  = (const float*)d_in[2];
    const float* b_rel  = (const float*)d_in[3];
    const float* w_root = (const float*)d_in[4];
    const float* w_fc1  = (const float*)d_in[5];
    const float* b_fc1  = (const float*)d_in[6];
    const float* w_fc2  = (const float*)d_in[7];
    const float* b_fc2  = (const float*)d_in[8];
    const int*   ei     = (const int*)d_in[9];
    const int*   batch  = (const int*)d_in[10];
    float* out = (float*)d_out;

    char* ws = (char*)d_ws;
    unsigned* yp   = (unsigned*)ws;                            // 3.2 MB (bf16x2)
    float* root    = (float*)(yp + (size_t)NN * 16);           // 6.4 MB
    uint2* part    = (uint2*)(root + (size_t)NN * DIM);        // 6.4 MB
    uint2* csr     = part + NE;                                // 6.4 MB
    int*   H       = (int*)(csr + NE);                         // HB*NB = 800 KB
    int*   colsum  = H + HB * NB;                              // NB
    int*   boff    = colsum + NB;                              // NB+1
    int*   csr_off = boff + NB + 2;                            // NB*BK+1
    float* pooled  = (float*)(csr_off + NB * BK + 2);          // 64 KB

    proj_kernel<<<NB, 256, 0, stream>>>(x, w_rel, w_root, b_rel, yp, root);
    histk<<<HB, 256, 0, stream>>>(ei, H, pooled);
    colscan<<<(NB + 255) / 256, 256, 0, stream>>>(H, colsum);
    bscan2<<<1, 256, 0, stream>>>(colsum, boff);
    partition_kernel<<<HB, 256, 0, stream>>>(ei, ew, H, boff, part);
    bucketsort_kernel<<<NB, 256, 0, stream>>>(part, boff, csr, csr_off);
    nodeagg_kernel<<<NN / 4, 256, 0, stream>>>(yp, root, csr_off, csr, batch, pooled);
    head_kernel<<<1, 512, 0, stream>>>(pooled, w_fc1, b_fc1, w_fc2, b_fc2, out);
}

// Round 11
// 99.233 us; speedup vs baseline: 2.7996x; 1.0568x over previous
//
#include <hip/hip_runtime.h>

#define NN 50000
#define NE 800000
#define NF 128
#define DIM 32
#define NG 500
#define BK 64                         // nodes per bucket
#define NB ((NN + BK - 1) / BK)       // 782 buckets
#define HB 256                        // histogram/partition blocks
#define CHUNK_E ((NE + HB - 1) / HB)  // 3125 edges per block
#define SC_CHUNK 4                    // 256*4 >= NB

__device__ __forceinline__ unsigned rne16(float f) {
    unsigned u = __float_as_uint(f);
    return (u + 0x7FFFu + ((u >> 16) & 1u)) >> 16;   // bf16 round-to-nearest-even
}

// ---------- k1: yp = pack_bf16(x@w_rel) ; root = x@w_root + b_rel ----------
__global__ __launch_bounds__(256) void proj_kernel(
    const float* __restrict__ x, const float* __restrict__ w_rel,
    const float* __restrict__ w_root, const float* __restrict__ b_rel,
    unsigned* __restrict__ yp, float* __restrict__ root)
{
    __shared__ float s_w[2 * NF * DIM];   // 32 KB
    int tid = threadIdx.x;
    {
        const float4* wr4 = reinterpret_cast<const float4*>(w_rel);
        const float4* wo4 = reinterpret_cast<const float4*>(w_root);
        float4* s4 = reinterpret_cast<float4*>(s_w);
#pragma unroll
        for (int j = 0; j < 4; ++j) s4[tid + j * 256]        = wr4[tid + j * 256];
#pragma unroll
        for (int j = 0; j < 4; ++j) s4[1024 + tid + j * 256] = wo4[tid + j * 256];
    }

    int cg = tid & 15;
    int rg = tid >> 4;
    int c0 = cg * 4;
    int rb = blockIdx.x * 64 + rg * 4;

    const float* Wb = (c0 < DIM) ? (s_w + c0) : (s_w + NF * DIM + (c0 - DIM));

    int r0s = min(rb + 0, NN - 1);
    int r1s = min(rb + 1, NN - 1);
    int r2s = min(rb + 2, NN - 1);
    int r3s = min(rb + 3, NN - 1);
    const float* x0 = x + (size_t)r0s * NF;
    const float* x1 = x + (size_t)r1s * NF;
    const float* x2 = x + (size_t)r2s * NF;
    const float* x3 = x + (size_t)r3s * NF;

    __syncthreads();

    float4 a0 = {0,0,0,0}, a1 = {0,0,0,0}, a2 = {0,0,0,0}, a3 = {0,0,0,0};

#define F4FMA(acc, xv, wa, wb_, wc, wd)                                \
    acc.x = fmaf(xv.x, wa.x, acc.x);  acc.y = fmaf(xv.x, wa.y, acc.y); \
    acc.z = fmaf(xv.x, wa.z, acc.z);  acc.w = fmaf(xv.x, wa.w, acc.w); \
    acc.x = fmaf(xv.y, wb_.x, acc.x); acc.y = fmaf(xv.y, wb_.y, acc.y); \
    acc.z = fmaf(xv.y, wb_.z, acc.z); acc.w = fmaf(xv.y, wb_.w, acc.w); \
    acc.x = fmaf(xv.z, wc.x, acc.x);  acc.y = fmaf(xv.z, wc.y, acc.y); \
    acc.z = fmaf(xv.z, wc.z, acc.z);  acc.w = fmaf(xv.z, wc.w, acc.w); \
    acc.x = fmaf(xv.w, wd.x, acc.x);  acc.y = fmaf(xv.w, wd.y, acc.y); \
    acc.z = fmaf(xv.w, wd.z, acc.z);  acc.w = fmaf(xv.w, wd.w, acc.w)

    float4 na = *reinterpret_cast<const float4*>(x0);
    float4 nb = *reinterpret_cast<const float4*>(x1);
    float4 nc = *reinterpret_cast<const float4*>(x2);
    float4 nd = *reinterpret_cast<const float4*>(x3);
#pragma unroll
    for (int k = 0; k < NF; k += 4) {
        float4 xa = na, xb = nb, xc = nc, xd = nd;
        if (k + 4 < NF) {
            na = *reinterpret_cast<const float4*>(x0 + k + 4);
            nb = *reinterpret_cast<const float4*>(x1 + k + 4);
            nc = *reinterpret_cast<const float4*>(x2 + k + 4);
            nd = *reinterpret_cast<const float4*>(x3 + k + 4);
        }
        float4 wa  = *reinterpret_cast<const float4*>(Wb + (k + 0) * DIM);
        float4 wb2 = *reinterpret_cast<const float4*>(Wb + (k + 1) * DIM);
        float4 wc  = *reinterpret_cast<const float4*>(Wb + (k + 2) * DIM);
        float4 wd  = *reinterpret_cast<const float4*>(Wb + (k + 3) * DIM);
        F4FMA(a0, xa, wa, wb2, wc, wd);
        F4FMA(a1, xb, wa, wb2, wc, wd);
        F4FMA(a2, xc, wa, wb2, wc, wd);
        F4FMA(a3, xd, wa, wb2, wc, wd);
    }
#undef F4FMA

    if (c0 < DIM) {
        int cp0 = c0 >> 1;
#define PACK2(v) make_uint2(rne16(v.x) | (rne16(v.y) << 16), rne16(v.z) | (rne16(v.w) << 16))
        if (rb + 0 < NN) *reinterpret_cast<uint2*>(yp + (size_t)(rb+0) * 16 + cp0) = PACK2(a0);
        if (rb + 1 < NN) *reinterpret_cast<uint2*>(yp + (size_t)(rb+1) * 16 + cp0) = PACK2(a1);
        if (rb + 2 < NN) *reinterpret_cast<uint2*>(yp + (size_t)(rb+2) * 16 + cp0) = PACK2(a2);
        if (rb + 3 < NN) *reinterpret_cast<uint2*>(yp + (size_t)(rb+3) * 16 + cp0) = PACK2(a3);
#undef PACK2
    } else {
        int cc = c0 - DIM;
        float4 bi = *reinterpret_cast<const float4*>(b_rel + cc);
        a0.x += bi.x; a0.y += bi.y; a0.z += bi.z; a0.w += bi.w;
        a1.x += bi.x; a1.y += bi.y; a1.z += bi.z; a1.w += bi.w;
        a2.x += bi.x; a2.y += bi.y; a2.z += bi.z; a2.w += bi.w;
        a3.x += bi.x; a3.y += bi.y; a3.z += bi.z; a3.w += bi.w;
        if (rb + 0 < NN) *reinterpret_cast<float4*>(root + (size_t)(rb+0) * DIM + cc) = a0;
        if (rb + 1 < NN) *reinterpret_cast<float4*>(root + (size_t)(rb+1) * DIM + cc) = a1;
        if (rb + 2 < NN) *reinterpret_cast<float4*>(root + (size_t)(rb+2) * DIM + cc) = a2;
        if (rb + 3 < NN) *reinterpret_cast<float4*>(root + (size_t)(rb+3) * DIM + cc) = a3;
    }
}

// ---------- k2: per-block bucket histogram (LDS) + zero pooled ----------
__global__ __launch_bounds__(256) void histk(
    const int* __restrict__ ei, int* __restrict__ H, float* __restrict__ pooled)
{
    int pi = blockIdx.x * 256 + threadIdx.x;
    if (pi < NG * DIM) pooled[pi] = 0.0f;

    __shared__ int sh[NB];
    int t = threadIdx.x;
    for (int i = t; i < NB; i += 256) sh[i] = 0;
    __syncthreads();
    int base = blockIdx.x * CHUNK_E;
    int end  = min(base + CHUNK_E, NE);
    for (int e = base + t; e < end; e += 256)
        atomicAdd(&sh[ei[NE + e] >> 6], 1);
    __syncthreads();
    for (int i = t; i < NB; i += 256) H[blockIdx.x * NB + i] = sh[i];
}

// ---------- k3a: column prefix over the HB block rows ----------
__global__ __launch_bounds__(256) void colscan(
    int* __restrict__ H, int* __restrict__ colsum)
{
    int b = blockIdx.x * 256 + threadIdx.x;
    if (b >= NB) return;
    int run = 0;
#pragma unroll 8
    for (int blk = 0; blk < HB; ++blk) {
        int v = H[blk * NB + b];
        H[blk * NB + b] = run;
        run += v;
    }
    colsum[b] = run;
}

// ---------- k3b: exclusive scan of colsum -> boff ----------
__global__ __launch_bounds__(256) void bscan2(
    const int* __restrict__ colsum, int* __restrict__ boff)
{
    __shared__ int s[256];
    int t = threadIdx.x;
    int v[SC_CHUNK];
    int sum = 0;
#pragma unroll
    for (int j = 0; j < SC_CHUNK; ++j) {
        int idx = t * SC_CHUNK + j;
        v[j] = (idx < NB) ? colsum[idx] : 0;
        sum += v[j];
    }
    s[t] = sum;
    __syncthreads();
    for (int o = 1; o < 256; o <<= 1) {
        int u = (t >= o) ? s[t - o] : 0;
        __syncthreads();
        s[t] += u;
        __syncthreads();
    }
    int base = s[t] - sum;
#pragma unroll
    for (int j = 0; j < SC_CHUNK; ++j) {
        int idx = t * SC_CHUNK + j;
        if (idx < NB) { boff[idx] = base; base += v[j]; }
    }
    if (t == 0) boff[NB] = NE;
}

// ---------- k4: deterministic bucket partition via LDS cursors ----------
__global__ __launch_bounds__(256) void partition_kernel(
    const int* __restrict__ ei, const float* __restrict__ ew,
    const int* __restrict__ H, const int* __restrict__ boff,
    uint2* __restrict__ part)
{
    __shared__ int cur[NB];
    int t = threadIdx.x;
    for (int i = t; i < NB; i += 256)
        cur[i] = boff[i] + H[blockIdx.x * NB + i];
    __syncthreads();
    int base = blockIdx.x * CHUNK_E;
    int end  = min(base + CHUNK_E, NE);
    for (int e = base + t; e < end; e += 256) {
        int s = ei[e], d = ei[NE + e];
        float w = ew[e];
        int b = d >> 6;
        int pos = atomicAdd(&cur[b], 1);   // LDS atomic, block-local
        part[pos] = make_uint2((unsigned)s | ((unsigned)(d & 63) << 16),
                               __float_as_uint(w));
    }
}

// ---------- k5: per-bucket counting sort -> per-node CSR (4B records) ----------
__global__ __launch_bounds__(256) void bucketsort_kernel(
    const uint2* __restrict__ part, const int* __restrict__ boff,
    unsigned* __restrict__ csr, int* __restrict__ csr_off)
{
    __shared__ int cnt[BK];
    __shared__ int cur[BK];
    int b = blockIdx.x, t = threadIdx.x;
    if (t < BK) cnt[t] = 0;
    __syncthreads();
    int s0 = boff[b], s1 = boff[b + 1];
    for (int e = s0 + t; e < s1; e += 256)
        atomicAdd(&cnt[part[e].x >> 16], 1);
    __syncthreads();
    if (t < BK) {
        int v = cnt[t];
        int inc = v;
#pragma unroll
        for (int o = 1; o < BK; o <<= 1) {
            int u = __shfl_up(inc, o, 64);
            if (t >= o) inc += u;
        }
        int ex = inc - v;
        cur[t] = ex;
        csr_off[b * BK + t] = s0 + ex;
    }
    if (b == NB - 1 && t == 0) csr_off[NB * BK] = NE;
    __syncthreads();
    for (int e = s0 + t; e < s1; e += 256) {
        uint2 pk = part[e];
        int nl = pk.x >> 16;
        int pos = atomicAdd(&cur[nl], 1);
        // record = src(16b) | bf16(w)(16b)
        csr[s0 + pos] = (pk.x & 0xFFFFu) | (rne16(__uint_as_float(pk.y)) << 16);
    }
}

// ---------- k6: wave64/node, 8 edge slots x 8 lanes (uint2 y loads) ----------
#define UIF __uint_as_float
__device__ __forceinline__ float blo(unsigned p) { return UIF(p << 16); }
__device__ __forceinline__ float bhi(unsigned p) { return UIF(p & 0xFFFF0000u); }

__global__ __launch_bounds__(256) void nodeagg_kernel(
    const uint2* __restrict__ ypq, const float* __restrict__ root,
    const int* __restrict__ csr_off, const unsigned* __restrict__ csr,
    const int* __restrict__ batch, float* __restrict__ pooled)
{
    __shared__ float s_p[4][DIM];
    __shared__ int   s_g[4];
    int t    = threadIdx.x;
    int w    = t >> 6;                    // wave id 0..3
    int lane = t & 63;
    int s    = lane >> 3;                 // edge slot 0..7
    int j    = lane & 7;                  // col quad -> cols 4j..4j+3
    int n    = blockIdx.x * 4 + w;        // NN % 4 == 0

    float v0 = 0.0f, v1 = 0.0f, v2 = 0.0f, v3 = 0.0f;
    int e1 = csr_off[n + 1];
    int e  = csr_off[n] + s;
    for (; e + 8 < e1; e += 16) {         // 16 edges per round (2 per slot)
        unsigned c0 = csr[e], c1 = csr[e + 8];
        uint2 p0 = ypq[(c0 & 0xFFFFu) * 8 + j];
        uint2 p1 = ypq[(c1 & 0xFFFFu) * 8 + j];
        float w0 = UIF(c0 & 0xFFFF0000u), w1 = UIF(c1 & 0xFFFF0000u);
        v0 = fmaf(w0, blo(p0.x), v0); v1 = fmaf(w0, bhi(p0.x), v1);
        v2 = fmaf(w0, blo(p0.y), v2); v3 = fmaf(w0, bhi(p0.y), v3);
        v0 = fmaf(w1, blo(p1.x), v0); v1 = fmaf(w1, bhi(p1.x), v1);
        v2 = fmaf(w1, blo(p1.y), v2); v3 = fmaf(w1, bhi(p1.y), v3);
    }
    for (; e < e1; e += 8) {
        unsigned cu = csr[e];
        uint2 p = ypq[(cu & 0xFFFFu) * 8 + j];
        float ww = UIF(cu & 0xFFFF0000u);
        v0 = fmaf(ww, blo(p.x), v0); v1 = fmaf(ww, bhi(p.x), v1);
        v2 = fmaf(ww, blo(p.y), v2); v3 = fmaf(ww, bhi(p.y), v3);
    }
    // combine the 8 edge slots (strides 8,16,32)
    v0 += __shfl_xor(v0, 8, 64); v0 += __shfl_xor(v0, 16, 64); v0 += __shfl_xor(v0, 32, 64);
    v1 += __shfl_xor(v1, 8, 64); v1 += __shfl_xor(v1, 16, 64); v1 += __shfl_xor(v1, 32, 64);
    v2 += __shfl_xor(v2, 8, 64); v2 += __shfl_xor(v2, 16, 64); v2 += __shfl_xor(v2, 32, 64);
    v3 += __shfl_xor(v3, 8, 64); v3 += __shfl_xor(v3, 16, 64); v3 += __shfl_xor(v3, 32, 64);

    if (s == 0) {                          // lanes 0..7 finalize 4 cols each
        float4 r = *reinterpret_cast<const float4*>(root + (size_t)n * DIM + 4 * j);
        float4 o;
        o.x = fmaxf(v0 + r.x, 0.0f);
        o.y = fmaxf(v1 + r.y, 0.0f);
        o.z = fmaxf(v2 + r.z, 0.0f);
        o.w = fmaxf(v3 + r.w, 0.0f);
        *reinterpret_cast<float4*>(&s_p[w][4 * j]) = o;
        if (j == 0) s_g[w] = batch[n];
    }
    __syncthreads();
    // combine the block's 4 consecutive nodes (batch sorted -> mostly same graph)
    if (t < DIM) {
        int curg = s_g[0];
        float run = s_p[0][t];
#pragma unroll
        for (int jj = 1; jj < 4; ++jj) {
            int g = s_g[jj];
            float v = s_p[jj][t];
            if (g != curg) {
                atomicAdd(&pooled[curg * DIM + t], run);
                curg = g; run = v;
            } else run += v;
        }
        atomicAdd(&pooled[curg * DIM + t], run);
    }
}

// ---------- k7: MLP head + log_softmax ----------
__global__ __launch_bounds__(512) void head_kernel(
    const float* __restrict__ pooled, const float* __restrict__ w_fc1,
    const float* __restrict__ b_fc1, const float* __restrict__ w_fc2,
    const float* __restrict__ b_fc2, float* __restrict__ out)
{
    __shared__ float s_fc1[DIM * DIM];
    __shared__ float s_b1[DIM];
    __shared__ float s_fc2[DIM * 2];
    __shared__ float s_b2[2];
    int tid = threadIdx.x;
    s_fc1[tid]       = w_fc1[tid];
    s_fc1[tid + 512] = w_fc1[tid + 512];
    if (tid < DIM * 2) s_fc2[tid] = w_fc2[tid];
    if (tid < DIM)     s_b1[tid]  = b_fc1[tid];
    if (tid < 2)       s_b2[tid]  = b_fc2[tid];
    __syncthreads();

    int g = tid;
    if (g >= NG) return;
    const float* p = pooled + g * DIM;
    float h2[DIM];
#pragma unroll
    for (int c = 0; c < DIM; ++c) {
        float a = s_b1[c];
#pragma unroll
        for (int k = 0; k < DIM; ++k)
            a = fmaf(p[k], s_fc1[k * DIM + c], a);
        h2[c] = a > 0.0f ? a : 0.0f;
    }
    float l0 = s_b2[0], l1 = s_b2[1];
#pragma unroll
    for (int c = 0; c < DIM; ++c) {
        l0 = fmaf(h2[c], s_fc2[c * 2 + 0], l0);
        l1 = fmaf(h2[c], s_fc2[c * 2 + 1], l1);
    }
    float m   = fmaxf(l0, l1);
    float lse = m + logf(expf(l0 - m) + expf(l1 - m));
    out[g * 2 + 0] = l0 - lse;
    out[g * 2 + 1] = l1 - lse;
}

extern "C" void kernel_launch(void* const* d_in, const int* in_sizes, int n_in,
                              void* d_out, int out_size, void* d_ws, size_t ws_size,
                              hipStream_t stream) {
    const float* x      = (const float*)d_in[0];
    const float* ew     = (const float*)d_in[1];
    const float* w_rel  = (const float*)d_in[2];
    const float* b_rel  = (const float*)d_in[3];
    const float* w_root = (const float*)d_in[4];
    const float* w_fc1  = (const float*)d_in[5];
    const float* b_fc1  = (const float*)d_in[6];
    const float* w_fc2  = (const float*)d_in[7];
    const float* b_fc2  = (const float*)d_in[8];
    const int*   ei     = (const int*)d_in[9];
    const int*   batch  = (const int*)d_in[10];
    float* out = (float*)d_out;

    char* ws = (char*)d_ws;
    unsigned* yp   = (unsigned*)ws;                            // 3.2 MB (bf16x2)
    float* root    = (float*)(yp + (size_t)NN * 16);           // 6.4 MB
    uint2* part    = (uint2*)(root + (size_t)NN * DIM);        // 6.4 MB
    unsigned* csr  = (unsigned*)(part + NE);                   // 3.2 MB (4B records)
    int*   H       = (int*)(csr + NE);                         // HB*NB = 800 KB
    int*   colsum  = H + HB * NB;                              // NB
    int*   boff    = colsum + NB;                              // NB+1
    int*   csr_off = boff + NB + 2;                            // NB*BK+1
    float* pooled  = (float*)(csr_off + NB * BK + 2);          // 64 KB

    proj_kernel<<<NB, 256, 0, stream>>>(x, w_rel, w_root, b_rel, yp, root);
    histk<<<HB, 256, 0, stream>>>(ei, H, pooled);
    colscan<<<(NB + 255) / 256, 256, 0, stream>>>(H, colsum);
    bscan2<<<1, 256, 0, stream>>>(colsum, boff);
    partition_kernel<<<HB, 256, 0, stream>>>(ei, ew, H, boff, part);
    bucketsort_kernel<<<NB, 256, 0, stream>>>(part, boff, csr, csr_off);
    nodeagg_kernel<<<NN / 4, 256, 0, stream>>>((const uint2*)yp, root, csr_off, csr, batch, pooled);
    head_kernel<<<1, 512, 0, stream>>>(pooled, w_fc1, b_fc1, w_fc2, b_fc2, out);
}